// Round 6
// baseline (709.585 us; speedup 1.0000x reference)
//
#include <hip/hip_runtime.h>

#define N_NODES 50000
#define D 128
#define R 8
#define E_EDGES 600000
#define NR (N_NODES * R)                 // 400000 (rel,dst) keys: key = r*N + dst
#define SCAN_BLOCKS ((NR + 1023) / 1024) // 391
#define EDGE_CAP 1024

typedef unsigned short ushort_t;
typedef unsigned int uint_t;
typedef __attribute__((ext_vector_type(8))) short short8;
typedef __attribute__((ext_vector_type(8))) ushort_t ushort8;
typedef __attribute__((ext_vector_type(4))) float f32x4;

// ws layout: [0,NR) int counts->offsets->ends ; [NR,NR+E) int bucket ;
// then WtH (9*128*128 ushort), WtL (same). Total ~4.6 MB.

static __device__ __forceinline__ ushort_t f2bf(float f) {
    uint_t u = __float_as_uint(f);
    uint_t r = u + 0x7fffu + ((u >> 16) & 1u);
    return (ushort_t)(r >> 16);
}
static __device__ __forceinline__ float bf2f(ushort_t h) {
    return __uint_as_float(((uint_t)h) << 16);
}

__global__ void __launch_bounds__(256)
count_kernel(const int* __restrict__ ei, const int* __restrict__ et,
             int* __restrict__ cnt) {
    int e = blockIdx.x * 256 + threadIdx.x;
    if (e < E_EDGES) {
        int dst = ei[E_EDGES + e];
        int r = et[e];
        atomicAdd(&cnt[r * N_NODES + dst], 1);
    }
}

__global__ void __launch_bounds__(256)
scan1_kernel(int* __restrict__ off, int* __restrict__ part) {
    __shared__ int wsum[4];
    int tid = threadIdx.x, lane = tid & 63, wid = tid >> 6;
    int base = blockIdx.x * 1024 + tid * 4;
    int c0 = 0, c1 = 0, c2 = 0, c3 = 0;
    if (base + 0 < NR) c0 = off[base + 0];
    if (base + 1 < NR) c1 = off[base + 1];
    if (base + 2 < NR) c2 = off[base + 2];
    if (base + 3 < NR) c3 = off[base + 3];
    int ts = c0 + c1 + c2 + c3;
    int v = ts;
#pragma unroll
    for (int o = 1; o < 64; o <<= 1) {
        int u = __shfl_up(v, o, 64);
        if (lane >= o) v += u;
    }
    if (lane == 63) wsum[wid] = v;
    __syncthreads();
    int wbase = 0;
#pragma unroll
    for (int w = 0; w < 4; ++w)
        if (w < wid) wbase += wsum[w];
    int excl = wbase + v - ts;
    if (base + 0 < NR) off[base + 0] = excl;
    if (base + 1 < NR) off[base + 1] = excl + c0;
    if (base + 2 < NR) off[base + 2] = excl + c0 + c1;
    if (base + 3 < NR) off[base + 3] = excl + c0 + c1 + c2;
    if (tid == 0) part[blockIdx.x] = wsum[0] + wsum[1] + wsum[2] + wsum[3];
}

__global__ void __launch_bounds__(512)
scan2_kernel(int* __restrict__ part) {
    __shared__ int sp[SCAN_BLOCKS];
    int tid = threadIdx.x;
    if (tid < SCAN_BLOCKS) sp[tid] = part[tid];
    __syncthreads();
    if (tid == 0) {
        int acc = 0;
        for (int i = 0; i < SCAN_BLOCKS; ++i) { int t = sp[i]; sp[i] = acc; acc += t; }
    }
    __syncthreads();
    if (tid < SCAN_BLOCKS) part[tid] = sp[tid];
}

__global__ void __launch_bounds__(256)
scan3_kernel(int* __restrict__ off, const int* __restrict__ part) {
    int p = part[blockIdx.x];
    int base = blockIdx.x * 1024 + threadIdx.x * 4;
#pragma unroll
    for (int i = 0; i < 4; ++i)
        if (base + i < NR) off[base + i] += p;
}

__global__ void __launch_bounds__(256)
bucket_kernel(const int* __restrict__ ei, const int* __restrict__ et,
              int* __restrict__ off, int* __restrict__ bucket) {
    int e = blockIdx.x * 256 + threadIdx.x;
    if (e < E_EDGES) {
        int src = ei[e];
        int dst = ei[E_EDGES + e];
        int r = et[e];
        int key = r * N_NODES + dst;
        int pos = atomicAdd(&off[key], 1);
        bucket[pos] = src;
    }
}

// One-time: W[r][k][col] fp32 -> Wt[r][col][k] bf16 hi/lo (B-fragment-friendly).
__global__ void __launch_bounds__(256)
wt_kernel(const float* __restrict__ W, const float* __restrict__ Wroot,
          ushort_t* __restrict__ WtH, ushort_t* __restrict__ WtL) {
    int r = blockIdx.x;
    const float* Wr = (r < 8) ? (W + ((size_t)r << 14)) : Wroot;
    __shared__ float T[32][129];
    int tid = threadIdx.x;
    for (int k0 = 0; k0 < D; k0 += 32) {
#pragma unroll
        for (int u = 0; u < 16; ++u) {
            int idx = tid + u * 256;
            T[idx >> 7][idx & 127] = Wr[(size_t)k0 * D + idx];
        }
        __syncthreads();
        int col = tid & 127, kh = tid >> 7;
        ushort8 h0, h1, l0, l1;
#pragma unroll
        for (int kk = 0; kk < 8; ++kk) {
            float f = T[kh * 16 + kk][col];
            ushort_t hb = f2bf(f);
            h0[kk] = hb; l0[kk] = f2bf(f - bf2f(hb));
        }
#pragma unroll
        for (int kk = 0; kk < 8; ++kk) {
            float f = T[kh * 16 + 8 + kk][col];
            ushort_t hb = f2bf(f);
            h1[kk] = hb; l1[kk] = f2bf(f - bf2f(hb));
        }
        size_t o = ((size_t)r << 14) + (size_t)col * D + k0 + kh * 16;
        *(ushort8*)&WtH[o] = h0; *(ushort8*)&WtH[o + 8] = h1;
        *(ushort8*)&WtL[o] = l0; *(ushort8*)&WtL[o + 8] = l1;
        __syncthreads();
    }
}

// One block = 64 dsts. Per r<8: block's bucket range is CONTIGUOUS (key=r*N+dst);
// stage edge list in LDS, edge-parallel gather (item = edge x col-quarter) with
// ds_add_f32 accumulation into fp32 At; mean-scale + bf16 hi/lo split at
// MFMA-fragment load. r=8 (root): A-frags read straight from x. acc carried
// across all 9 relations; epilogue bias+ReLU (MFMA D layout verified round 5).
__global__ void __launch_bounds__(256, 4)
fused_kernel(const float* __restrict__ x,
             const ushort_t* __restrict__ WtH, const ushort_t* __restrict__ WtL,
             const float* __restrict__ bias, const int* __restrict__ ends,
             const int* __restrict__ bucket, float* __restrict__ out) {
    __shared__ float At[64][132];   // fp32 accumulation, 33792 B, 16B-aligned rows
    __shared__ int elist[EDGE_CAP]; // 4 KB staged src ids
    __shared__ int seg[64];         // ABSOLUTE segment ends for the 64 dsts
    __shared__ float sinv[64];
    __shared__ float bs[128];
    __shared__ int sbase;

    int tid = threadIdx.x;
    int lane = tid & 63;
    int wave = tid >> 6;
    int mrow = lane & 15;
    int kg = lane >> 4;
    int n0 = blockIdx.x * 64;
    if (tid < 128) bs[tid] = bias[tid];

    f32x4 acc[8];
#pragma unroll
    for (int t = 0; t < 8; ++t) acc[t] = (f32x4){0.f, 0.f, 0.f, 0.f};

    for (int r = 0; r < R; ++r) {
        __syncthreads();  // previous relation's MFMA done reading At
        // clear At (8448 floats = 33 per thread, exact)
#pragma unroll
        for (int u = 0; u < 33; ++u) ((float*)At)[tid + u * 256] = 0.f;
        if (tid < 64) {
            int n = n0 + tid;
            if (n > N_NODES - 1) n = N_NODES - 1;  // clamp: dup end == block total
            int key = r * N_NODES + n;
            int e1 = ends[key];
            int e0 = (key == 0) ? 0 : ends[key - 1];
            int c = e1 - e0;
            sinv[tid] = (c > 0) ? 1.0f / (float)c : 0.0f;
            seg[tid] = e1;
            if (tid == 0) sbase = e0;
        }
        __syncthreads();
        int base = sbase;
        int nE = seg[63] - base;

        for (int c0 = 0; c0 < nE; c0 += EDGE_CAP) {
            int cN = nE - c0;
            if (cN > EDGE_CAP) cN = EDGE_CAP;
            for (int i = tid; i < cN; i += 256) elist[i] = bucket[base + c0 + i];
            __syncthreads();
            for (int item = tid; item < 4 * cN; item += 256) {
                int el = item >> 2, q = item & 3;
                int p = base + c0 + el;  // absolute edge position
                // lower_bound: first j with p < seg[j]
                int lo = 0, hi = 63;
                while (lo < hi) {
                    int mid = (lo + hi) >> 1;
                    if (p < seg[mid]) hi = mid; else lo = mid + 1;
                }
                int src = elist[el];
                const float4* xp = (const float4*)(x + (size_t)src * D + q * 32);
                float4 v[8];
#pragma unroll
                for (int u = 0; u < 8; ++u) v[u] = xp[u];
                float* rowp = &At[lo][q * 32];
#pragma unroll
                for (int u = 0; u < 8; ++u) {
                    atomicAdd(rowp + u * 4 + 0, v[u].x);
                    atomicAdd(rowp + u * 4 + 1, v[u].y);
                    atomicAdd(rowp + u * 4 + 2, v[u].z);
                    atomicAdd(rowp + u * 4 + 3, v[u].w);
                }
            }
            __syncthreads();
        }

        // MFMA: wave owns dst rows wave*16..+15; mean-scale + hi/lo split here
        const ushort_t* WH = WtH + ((size_t)r << 14);
        const ushort_t* WL = WtL + ((size_t)r << 14);
        int row = wave * 16 + mrow;
        float iv = sinv[row];
#pragma unroll
        for (int kstep = 0; kstep < 4; ++kstep) {
            int kofs = kstep * 32 + kg * 8;
            float4 f0 = *(const float4*)&At[row][kofs];
            float4 f1 = *(const float4*)&At[row][kofs + 4];
            float fv[8] = {f0.x, f0.y, f0.z, f0.w, f1.x, f1.y, f1.z, f1.w};
            short8 ah, al;
#pragma unroll
            for (int j = 0; j < 8; ++j) {
                float f = fv[j] * iv;
                ushort_t hb = f2bf(f);
                ah[j] = (short)hb;
                al[j] = (short)f2bf(f - bf2f(hb));
            }
#pragma unroll
            for (int nt = 0; nt < 8; ++nt) {
                int col = nt * 16 + mrow;
                short8 bh = *(const short8*)&WH[(size_t)col * D + kofs];
                short8 bl = *(const short8*)&WL[(size_t)col * D + kofs];
                acc[nt] = __builtin_amdgcn_mfma_f32_16x16x32_bf16(ah, bh, acc[nt], 0, 0, 0);
                acc[nt] = __builtin_amdgcn_mfma_f32_16x16x32_bf16(ah, bl, acc[nt], 0, 0, 0);
                acc[nt] = __builtin_amdgcn_mfma_f32_16x16x32_bf16(al, bh, acc[nt], 0, 0, 0);
            }
        }
    }

    // root relation r=8: A-frags straight from x (no LDS, no barrier)
    {
        const ushort_t* WH = WtH + ((size_t)8 << 14);
        const ushort_t* WL = WtL + ((size_t)8 << 14);
        int n = n0 + wave * 16 + mrow;
#pragma unroll
        for (int kstep = 0; kstep < 4; ++kstep) {
            int kofs = kstep * 32 + kg * 8;
            float fv[8] = {0.f, 0.f, 0.f, 0.f, 0.f, 0.f, 0.f, 0.f};
            if (n < N_NODES) {
                const float4* xp = (const float4*)(x + (size_t)n * D + kofs);
                float4 f0 = xp[0], f1 = xp[1];
                fv[0] = f0.x; fv[1] = f0.y; fv[2] = f0.z; fv[3] = f0.w;
                fv[4] = f1.x; fv[5] = f1.y; fv[6] = f1.z; fv[7] = f1.w;
            }
            short8 ah, al;
#pragma unroll
            for (int j = 0; j < 8; ++j) {
                float f = fv[j];
                ushort_t hb = f2bf(f);
                ah[j] = (short)hb;
                al[j] = (short)f2bf(f - bf2f(hb));
            }
#pragma unroll
            for (int nt = 0; nt < 8; ++nt) {
                int col = nt * 16 + mrow;
                short8 bh = *(const short8*)&WH[(size_t)col * D + kofs];
                short8 bl = *(const short8*)&WL[(size_t)col * D + kofs];
                acc[nt] = __builtin_amdgcn_mfma_f32_16x16x32_bf16(ah, bh, acc[nt], 0, 0, 0);
                acc[nt] = __builtin_amdgcn_mfma_f32_16x16x32_bf16(ah, bl, acc[nt], 0, 0, 0);
                acc[nt] = __builtin_amdgcn_mfma_f32_16x16x32_bf16(al, bh, acc[nt], 0, 0, 0);
            }
        }
    }

    // epilogue: D layout col=lane&15, row=(lane>>4)*4+j (verified round 5)
#pragma unroll
    for (int nt = 0; nt < 8; ++nt) {
        int col = nt * 16 + mrow;
        float bb = bs[col];
#pragma unroll
        for (int j = 0; j < 4; ++j) {
            int nn = n0 + wave * 16 + kg * 4 + j;
            if (nn < N_NODES) {
                float v = acc[nt][j] + bb;
                out[(size_t)nn * D + col] = v > 0.f ? v : 0.f;
            }
        }
    }
}

extern "C" void kernel_launch(void* const* d_in, const int* in_sizes, int n_in,
                              void* d_out, int out_size, void* d_ws, size_t ws_size,
                              hipStream_t stream) {
    const float* x     = (const float*)d_in[0];
    const int*   ei    = (const int*)d_in[1];
    const int*   et    = (const int*)d_in[2];
    const float* W     = (const float*)d_in[3];
    const float* Wroot = (const float*)d_in[4];
    const float* b     = (const float*)d_in[5];
    float* out = (float*)d_out;
    int* ws = (int*)d_ws;
    int* off = ws;                                   // NR ints
    int* bucket = ws + NR;                           // E ints
    ushort_t* WtH = (ushort_t*)(ws + NR + E_EDGES);  // 9*16384 ushorts
    ushort_t* WtL = WtH + 9 * 16384;

    hipMemsetAsync(d_ws, 0, (size_t)NR * sizeof(int), stream);

    count_kernel<<<(E_EDGES + 255) / 256, 256, 0, stream>>>(ei, et, off);
    wt_kernel<<<9, 256, 0, stream>>>(W, Wroot, WtH, WtL);
    scan1_kernel<<<SCAN_BLOCKS, 256, 0, stream>>>(off, bucket);
    scan2_kernel<<<1, 512, 0, stream>>>(bucket);
    scan3_kernel<<<SCAN_BLOCKS, 256, 0, stream>>>(off, bucket);
    bucket_kernel<<<(E_EDGES + 255) / 256, 256, 0, stream>>>(ei, et, off, bucket);
    fused_kernel<<<(N_NODES + 63) / 64, 256, 0, stream>>>(x, WtH, WtL, b, off,
                                                          bucket, out);
}

// Round 7
// 699.370 us; speedup vs baseline: 1.0146x; 1.0146x over previous
//
#include <hip/hip_runtime.h>

#define N_NODES 50000
#define D 128
#define R 8
#define E_EDGES 600000
#define NR (N_NODES * R)                 // 400000 (rel,dst) keys: key = r*N + dst
#define SCAN_BLOCKS ((NR + 1023) / 1024) // 391

typedef unsigned short ushort_t;
typedef unsigned int uint_t;
typedef __attribute__((ext_vector_type(8))) short short8;
typedef __attribute__((ext_vector_type(8))) ushort_t ushort8;
typedef __attribute__((ext_vector_type(4))) float f32x4;

// ws layout: [0,NR) int counts->offsets->ends ; [NR,NR+E) packed bucket ;
// then WtH (9*128*128 ushort), WtL (same). Total ~4.6 MB.

static __device__ __forceinline__ ushort_t f2bf(float f) {
    uint_t u = __float_as_uint(f);
    uint_t r = u + 0x7fffu + ((u >> 16) & 1u);
    return (ushort_t)(r >> 16);
}
static __device__ __forceinline__ float bf2f(ushort_t h) {
    return __uint_as_float(((uint_t)h) << 16);
}

__global__ void __launch_bounds__(256)
count_kernel(const int* __restrict__ ei, const int* __restrict__ et,
             int* __restrict__ cnt) {
    int e = blockIdx.x * 256 + threadIdx.x;
    if (e < E_EDGES) {
        int dst = ei[E_EDGES + e];
        int r = et[e];
        atomicAdd(&cnt[r * N_NODES + dst], 1);
    }
}

__global__ void __launch_bounds__(256)
scan1_kernel(int* __restrict__ off, int* __restrict__ part) {
    __shared__ int wsum[4];
    int tid = threadIdx.x, lane = tid & 63, wid = tid >> 6;
    int base = blockIdx.x * 1024 + tid * 4;
    int c0 = 0, c1 = 0, c2 = 0, c3 = 0;
    if (base + 0 < NR) c0 = off[base + 0];
    if (base + 1 < NR) c1 = off[base + 1];
    if (base + 2 < NR) c2 = off[base + 2];
    if (base + 3 < NR) c3 = off[base + 3];
    int ts = c0 + c1 + c2 + c3;
    int v = ts;
#pragma unroll
    for (int o = 1; o < 64; o <<= 1) {
        int u = __shfl_up(v, o, 64);
        if (lane >= o) v += u;
    }
    if (lane == 63) wsum[wid] = v;
    __syncthreads();
    int wbase = 0;
#pragma unroll
    for (int w = 0; w < 4; ++w)
        if (w < wid) wbase += wsum[w];
    int excl = wbase + v - ts;
    if (base + 0 < NR) off[base + 0] = excl;
    if (base + 1 < NR) off[base + 1] = excl + c0;
    if (base + 2 < NR) off[base + 2] = excl + c0 + c1;
    if (base + 3 < NR) off[base + 3] = excl + c0 + c1 + c2;
    if (tid == 0) part[blockIdx.x] = wsum[0] + wsum[1] + wsum[2] + wsum[3];
}

__global__ void __launch_bounds__(512)
scan2_kernel(int* __restrict__ part) {
    __shared__ int sp[SCAN_BLOCKS];
    int tid = threadIdx.x;
    if (tid < SCAN_BLOCKS) sp[tid] = part[tid];
    __syncthreads();
    if (tid == 0) {
        int acc = 0;
        for (int i = 0; i < SCAN_BLOCKS; ++i) { int t = sp[i]; sp[i] = acc; acc += t; }
    }
    __syncthreads();
    if (tid < SCAN_BLOCKS) part[tid] = sp[tid];
}

__global__ void __launch_bounds__(256)
scan3_kernel(int* __restrict__ off, const int* __restrict__ part) {
    int p = part[blockIdx.x];
    int base = blockIdx.x * 1024 + threadIdx.x * 4;
#pragma unroll
    for (int i = 0; i < 4; ++i)
        if (base + i < NR) off[base + i] += p;
}

// Scatter PACKED (src | dst_local<<17 | rel<<23) into (rel,dst)-sorted bucket.
// dst_local = dst & 63 (blocks are 64-aligned). Turns off[] into segment ENDS.
__global__ void __launch_bounds__(256)
bucket_kernel(const int* __restrict__ ei, const int* __restrict__ et,
              int* __restrict__ off, uint_t* __restrict__ bucket) {
    int e = blockIdx.x * 256 + threadIdx.x;
    if (e < E_EDGES) {
        int src = ei[e];
        int dst = ei[E_EDGES + e];
        int r = et[e];
        int key = r * N_NODES + dst;
        int pos = atomicAdd(&off[key], 1);
        bucket[pos] = (uint_t)src | ((uint_t)(dst & 63) << 17) | ((uint_t)r << 23);
    }
}

// One-time: W[r][k][col] fp32 -> Wt[r][col][k] bf16 hi/lo (B-fragment-friendly).
__global__ void __launch_bounds__(256)
wt_kernel(const float* __restrict__ W, const float* __restrict__ Wroot,
          ushort_t* __restrict__ WtH, ushort_t* __restrict__ WtL) {
    int r = blockIdx.x;
    const float* Wr = (r < 8) ? (W + ((size_t)r << 14)) : Wroot;
    __shared__ float T[32][129];
    int tid = threadIdx.x;
    for (int k0 = 0; k0 < D; k0 += 32) {
#pragma unroll
        for (int u = 0; u < 16; ++u) {
            int idx = tid + u * 256;
            T[idx >> 7][idx & 127] = Wr[(size_t)k0 * D + idx];
        }
        __syncthreads();
        int col = tid & 127, kh = tid >> 7;
        ushort8 h0, h1, l0, l1;
#pragma unroll
        for (int kk = 0; kk < 8; ++kk) {
            float f = T[kh * 16 + kk][col];
            ushort_t hb = f2bf(f);
            h0[kk] = hb; l0[kk] = f2bf(f - bf2f(hb));
        }
#pragma unroll
        for (int kk = 0; kk < 8; ++kk) {
            float f = T[kh * 16 + 8 + kk][col];
            ushort_t hb = f2bf(f);
            h1[kk] = hb; l1[kk] = f2bf(f - bf2f(hb));
        }
        size_t o = ((size_t)r << 14) + (size_t)col * D + k0 + kh * 16;
        *(ushort8*)&WtH[o] = h0; *(ushort8*)&WtH[o + 8] = h1;
        *(ushort8*)&WtL[o] = l0; *(ushort8*)&WtL[o + 8] = l1;
        __syncthreads();
    }
}

// One block = 64 dsts. Per r<8: block's bucket range is contiguous (key=r*N+dst).
// Edge-parallel gather: item = (edge, 16B chunk), no binary search (dst_local
// packed in bucket word), lanes 0..31 of a wave read one edge's full 512B row
// coalesced; accumulate via ds_add_f32 into fp32 At. Mean-scale + bf16 hi/lo at
// MFMA-fragment load. r=8 (root): A-frags straight from x. acc carried across
// all 9 relations; epilogue bias+ReLU (MFMA layouts verified rounds 5-6).
__global__ void __launch_bounds__(256, 4)
fused_kernel(const float* __restrict__ x,
             const ushort_t* __restrict__ WtH, const ushort_t* __restrict__ WtL,
             const float* __restrict__ bias, const int* __restrict__ ends,
             const uint_t* __restrict__ bucket, float* __restrict__ out) {
    __shared__ float At[64][132];   // fp32 accumulation, 33792 B
    __shared__ float sinv[64];
    __shared__ int sEnd[64];
    __shared__ float bs[128];
    __shared__ int sBase;

    int tid = threadIdx.x;
    int lane = tid & 63;
    int wave = tid >> 6;
    int mrow = lane & 15;
    int kg = lane >> 4;
    int n0 = blockIdx.x * 64;
    if (tid < 128) bs[tid] = bias[tid];

    f32x4 acc[8];
#pragma unroll
    for (int t = 0; t < 8; ++t) acc[t] = (f32x4){0.f, 0.f, 0.f, 0.f};

    for (int r = 0; r < R; ++r) {
        __syncthreads();  // previous relation's MFMA done reading At
        // clear At (8448 floats = 33 per thread, exact)
#pragma unroll
        for (int u = 0; u < 33; ++u) ((float*)At)[tid + u * 256] = 0.f;
        if (tid < 64) {
            int n = n0 + tid;
            if (n > N_NODES - 1) n = N_NODES - 1;  // clamp: dup end == range end
            int key = r * N_NODES + n;
            int e1 = ends[key];
            int e0 = (key == 0) ? 0 : ends[key - 1];
            int c = e1 - e0;
            sinv[tid] = (c > 0) ? 1.0f / (float)c : 0.0f;
            sEnd[tid] = e1;
            if (tid == 0) sBase = e0;
        }
        __syncthreads();
        int base = sBase;
        int nItems = (sEnd[63] - base) << 5;  // 32 x 16B chunks per edge

        // independent iterations: bucket word -> 16B x chunk -> 4 ds_add_f32
        for (int i = tid; i < nItems; i += 256) {
            uint_t v = bucket[base + (i >> 5)];
            int src = v & 0x1FFFF;
            int dl = (v >> 17) & 63;
            int ch = i & 31;
            float4 xv = *(const float4*)(x + (size_t)src * D + ch * 4);
            float* rp = &At[dl][ch * 4];
            atomicAdd(rp + 0, xv.x);
            atomicAdd(rp + 1, xv.y);
            atomicAdd(rp + 2, xv.z);
            atomicAdd(rp + 3, xv.w);
        }
        __syncthreads();

        // MFMA: wave owns dst rows wave*16..+15; mean-scale + hi/lo split here
        const ushort_t* WH = WtH + ((size_t)r << 14);
        const ushort_t* WL = WtL + ((size_t)r << 14);
        int row = wave * 16 + mrow;
        float iv = sinv[row];
#pragma unroll
        for (int kstep = 0; kstep < 4; ++kstep) {
            int kofs = kstep * 32 + kg * 8;
            float4 f0 = *(const float4*)&At[row][kofs];
            float4 f1 = *(const float4*)&At[row][kofs + 4];
            float fv[8] = {f0.x, f0.y, f0.z, f0.w, f1.x, f1.y, f1.z, f1.w};
            short8 ah, al;
#pragma unroll
            for (int j = 0; j < 8; ++j) {
                float f = fv[j] * iv;
                ushort_t hb = f2bf(f);
                ah[j] = (short)hb;
                al[j] = (short)f2bf(f - bf2f(hb));
            }
#pragma unroll
            for (int nt = 0; nt < 8; ++nt) {
                int col = nt * 16 + mrow;
                short8 bh = *(const short8*)&WH[(size_t)col * D + kofs];
                short8 bl = *(const short8*)&WL[(size_t)col * D + kofs];
                acc[nt] = __builtin_amdgcn_mfma_f32_16x16x32_bf16(ah, bh, acc[nt], 0, 0, 0);
                acc[nt] = __builtin_amdgcn_mfma_f32_16x16x32_bf16(ah, bl, acc[nt], 0, 0, 0);
                acc[nt] = __builtin_amdgcn_mfma_f32_16x16x32_bf16(al, bh, acc[nt], 0, 0, 0);
            }
        }
    }

    // root relation r=8: A-frags straight from x (no LDS, no barrier)
    {
        const ushort_t* WH = WtH + ((size_t)8 << 14);
        const ushort_t* WL = WtL + ((size_t)8 << 14);
        int n = n0 + wave * 16 + mrow;
#pragma unroll
        for (int kstep = 0; kstep < 4; ++kstep) {
            int kofs = kstep * 32 + kg * 8;
            float fv[8] = {0.f, 0.f, 0.f, 0.f, 0.f, 0.f, 0.f, 0.f};
            if (n < N_NODES) {
                const float4* xp = (const float4*)(x + (size_t)n * D + kofs);
                float4 f0 = xp[0], f1 = xp[1];
                fv[0] = f0.x; fv[1] = f0.y; fv[2] = f0.z; fv[3] = f0.w;
                fv[4] = f1.x; fv[5] = f1.y; fv[6] = f1.z; fv[7] = f1.w;
            }
            short8 ah, al;
#pragma unroll
            for (int j = 0; j < 8; ++j) {
                float f = fv[j];
                ushort_t hb = f2bf(f);
                ah[j] = (short)hb;
                al[j] = (short)f2bf(f - bf2f(hb));
            }
#pragma unroll
            for (int nt = 0; nt < 8; ++nt) {
                int col = nt * 16 + mrow;
                short8 bh = *(const short8*)&WH[(size_t)col * D + kofs];
                short8 bl = *(const short8*)&WL[(size_t)col * D + kofs];
                acc[nt] = __builtin_amdgcn_mfma_f32_16x16x32_bf16(ah, bh, acc[nt], 0, 0, 0);
                acc[nt] = __builtin_amdgcn_mfma_f32_16x16x32_bf16(ah, bl, acc[nt], 0, 0, 0);
                acc[nt] = __builtin_amdgcn_mfma_f32_16x16x32_bf16(al, bh, acc[nt], 0, 0, 0);
            }
        }
    }

    // epilogue: D layout col=lane&15, row=(lane>>4)*4+j (verified round 5)
#pragma unroll
    for (int nt = 0; nt < 8; ++nt) {
        int col = nt * 16 + mrow;
        float bb = bs[col];
#pragma unroll
        for (int j = 0; j < 4; ++j) {
            int nn = n0 + wave * 16 + kg * 4 + j;
            if (nn < N_NODES) {
                float v = acc[nt][j] + bb;
                out[(size_t)nn * D + col] = v > 0.f ? v : 0.f;
            }
        }
    }
}

extern "C" void kernel_launch(void* const* d_in, const int* in_sizes, int n_in,
                              void* d_out, int out_size, void* d_ws, size_t ws_size,
                              hipStream_t stream) {
    const float* x     = (const float*)d_in[0];
    const int*   ei    = (const int*)d_in[1];
    const int*   et    = (const int*)d_in[2];
    const float* W     = (const float*)d_in[3];
    const float* Wroot = (const float*)d_in[4];
    const float* b     = (const float*)d_in[5];
    float* out = (float*)d_out;
    int* ws = (int*)d_ws;
    int* off = ws;                                   // NR ints
    uint_t* bucket = (uint_t*)(ws + NR);             // E packed words
    ushort_t* WtH = (ushort_t*)(ws + NR + E_EDGES);  // 9*16384 ushorts
    ushort_t* WtL = WtH + 9 * 16384;

    hipMemsetAsync(d_ws, 0, (size_t)NR * sizeof(int), stream);

    count_kernel<<<(E_EDGES + 255) / 256, 256, 0, stream>>>(ei, et, off);
    wt_kernel<<<9, 256, 0, stream>>>(W, Wroot, WtH, WtL);
    scan1_kernel<<<SCAN_BLOCKS, 256, 0, stream>>>(off, (int*)bucket);
    scan2_kernel<<<1, 512, 0, stream>>>((int*)bucket);
    scan3_kernel<<<SCAN_BLOCKS, 256, 0, stream>>>(off, (int*)bucket);
    bucket_kernel<<<(E_EDGES + 255) / 256, 256, 0, stream>>>(ei, et, off, bucket);
    fused_kernel<<<(N_NODES + 63) / 64, 256, 0, stream>>>(x, WtH, WtL, b, off,
                                                          bucket, out);
}

// Round 8
// 451.870 us; speedup vs baseline: 1.5703x; 1.5477x over previous
//
#include <hip/hip_runtime.h>

#define N_NODES 50000
#define D 128
#define R 8
#define E_EDGES 600000
#define NR (N_NODES * R)                 // 400000 (rel,dst) keys: key = r*N + dst
#define SCAN_BLOCKS ((NR + 1023) / 1024) // 391

typedef unsigned short ushort_t;
typedef unsigned int uint_t;
typedef __attribute__((ext_vector_type(8))) short short8;
typedef __attribute__((ext_vector_type(8))) ushort_t ushort8;
typedef __attribute__((ext_vector_type(4))) float f32x4;

// ws layout: [0,NR) int counts->offsets->ends ; [NR,NR+E) packed bucket ;
// WtH (9*128*128 ushort), WtL (same)  => 4,589,824 B ; then (big-ws path only)
// M = NR*D fp32 means (204.8 MB). Big path needs ~209.4 MB total.
#define FIXED_WS_BYTES 4589824
#define BIG_WS_BYTES (FIXED_WS_BYTES + (size_t)NR * D * 4)

static __device__ __forceinline__ ushort_t f2bf(float f) {
    uint_t u = __float_as_uint(f);
    uint_t r = u + 0x7fffu + ((u >> 16) & 1u);
    return (ushort_t)(r >> 16);
}
static __device__ __forceinline__ float bf2f(ushort_t h) {
    return __uint_as_float(((uint_t)h) << 16);
}

__global__ void __launch_bounds__(256)
count_kernel(const int* __restrict__ ei, const int* __restrict__ et,
             int* __restrict__ cnt) {
    int e = blockIdx.x * 256 + threadIdx.x;
    if (e < E_EDGES) {
        int dst = ei[E_EDGES + e];
        int r = et[e];
        atomicAdd(&cnt[r * N_NODES + dst], 1);
    }
}

__global__ void __launch_bounds__(256)
scan1_kernel(int* __restrict__ off, int* __restrict__ part) {
    __shared__ int wsum[4];
    int tid = threadIdx.x, lane = tid & 63, wid = tid >> 6;
    int base = blockIdx.x * 1024 + tid * 4;
    int c0 = 0, c1 = 0, c2 = 0, c3 = 0;
    if (base + 0 < NR) c0 = off[base + 0];
    if (base + 1 < NR) c1 = off[base + 1];
    if (base + 2 < NR) c2 = off[base + 2];
    if (base + 3 < NR) c3 = off[base + 3];
    int ts = c0 + c1 + c2 + c3;
    int v = ts;
#pragma unroll
    for (int o = 1; o < 64; o <<= 1) {
        int u = __shfl_up(v, o, 64);
        if (lane >= o) v += u;
    }
    if (lane == 63) wsum[wid] = v;
    __syncthreads();
    int wbase = 0;
#pragma unroll
    for (int w = 0; w < 4; ++w)
        if (w < wid) wbase += wsum[w];
    int excl = wbase + v - ts;
    if (base + 0 < NR) off[base + 0] = excl;
    if (base + 1 < NR) off[base + 1] = excl + c0;
    if (base + 2 < NR) off[base + 2] = excl + c0 + c1;
    if (base + 3 < NR) off[base + 3] = excl + c0 + c1 + c2;
    if (tid == 0) part[blockIdx.x] = wsum[0] + wsum[1] + wsum[2] + wsum[3];
}

__global__ void __launch_bounds__(512)
scan2_kernel(int* __restrict__ part) {
    __shared__ int sp[SCAN_BLOCKS];
    int tid = threadIdx.x;
    if (tid < SCAN_BLOCKS) sp[tid] = part[tid];
    __syncthreads();
    if (tid == 0) {
        int acc = 0;
        for (int i = 0; i < SCAN_BLOCKS; ++i) { int t = sp[i]; sp[i] = acc; acc += t; }
    }
    __syncthreads();
    if (tid < SCAN_BLOCKS) part[tid] = sp[tid];
}

__global__ void __launch_bounds__(256)
scan3_kernel(int* __restrict__ off, const int* __restrict__ part) {
    int p = part[blockIdx.x];
    int base = blockIdx.x * 1024 + threadIdx.x * 4;
#pragma unroll
    for (int i = 0; i < 4; ++i)
        if (base + i < NR) off[base + i] += p;
}

// Packed (src | dst_local<<17 | rel<<23) into (rel,dst)-sorted bucket.
__global__ void __launch_bounds__(256)
bucket_kernel(const int* __restrict__ ei, const int* __restrict__ et,
              int* __restrict__ off, uint_t* __restrict__ bucket) {
    int e = blockIdx.x * 256 + threadIdx.x;
    if (e < E_EDGES) {
        int src = ei[e];
        int dst = ei[E_EDGES + e];
        int r = et[e];
        int key = r * N_NODES + dst;
        int pos = atomicAdd(&off[key], 1);
        bucket[pos] = (uint_t)src | ((uint_t)(dst & 63) << 17) | ((uint_t)r << 23);
    }
}

// One-time: W[r][k][col] fp32 -> Wt[r][col][k] bf16 hi/lo.
__global__ void __launch_bounds__(256)
wt_kernel(const float* __restrict__ W, const float* __restrict__ Wroot,
          ushort_t* __restrict__ WtH, ushort_t* __restrict__ WtL) {
    int r = blockIdx.x;
    const float* Wr = (r < 8) ? (W + ((size_t)r << 14)) : Wroot;
    __shared__ float T[32][129];
    int tid = threadIdx.x;
    for (int k0 = 0; k0 < D; k0 += 32) {
#pragma unroll
        for (int u = 0; u < 16; ++u) {
            int idx = tid + u * 256;
            T[idx >> 7][idx & 127] = Wr[(size_t)k0 * D + idx];
        }
        __syncthreads();
        int col = tid & 127, kh = tid >> 7;
        ushort8 h0, h1, l0, l1;
#pragma unroll
        for (int kk = 0; kk < 8; ++kk) {
            float f = T[kh * 16 + kk][col];
            ushort_t hb = f2bf(f);
            h0[kk] = hb; l0[kk] = f2bf(f - bf2f(hb));
        }
#pragma unroll
        for (int kk = 0; kk < 8; ++kk) {
            float f = T[kh * 16 + 8 + kk][col];
            ushort_t hb = f2bf(f);
            h1[kk] = hb; l1[kk] = f2bf(f - bf2f(hb));
        }
        size_t o = ((size_t)r << 14) + (size_t)col * D + k0 + kh * 16;
        *(ushort8*)&WtH[o] = h0; *(ushort8*)&WtH[o + 8] = h1;
        *(ushort8*)&WtL[o] = l0; *(ushort8*)&WtL[o + 8] = l1;
        __syncthreads();
    }
}

// BIG-WS PATH kernel 1: one 16-lane group per (rel,dst) key; mean of x_src
// rows over the segment; coalesced 512B row reads/writes; no atomics/barriers.
__global__ void __launch_bounds__(256)
mean_kernel(const float* __restrict__ x, const int* __restrict__ ends,
            const uint_t* __restrict__ bucket, float* __restrict__ M) {
    int tid = threadIdx.x;
    int g = blockIdx.x * 16 + (tid >> 4);  // key index, grid covers NR exactly
    int l = tid & 15;
    int e1 = ends[g];
    int e0 = (g == 0) ? 0 : ends[g - 1];
    float4 a0 = {0.f, 0.f, 0.f, 0.f}, a1 = {0.f, 0.f, 0.f, 0.f};
    for (int p = e0; p < e1; ++p) {
        int src = bucket[p] & 0x1FFFF;
        const float4* xp = (const float4*)(x + (size_t)src * D + l * 8);
        float4 v0 = xp[0], v1 = xp[1];
        a0.x += v0.x; a0.y += v0.y; a0.z += v0.z; a0.w += v0.w;
        a1.x += v1.x; a1.y += v1.y; a1.z += v1.z; a1.w += v1.w;
    }
    float inv = (e1 > e0) ? 1.0f / (float)(e1 - e0) : 0.0f;
    a0.x *= inv; a0.y *= inv; a0.z *= inv; a0.w *= inv;
    a1.x *= inv; a1.y *= inv; a1.z *= inv; a1.w *= inv;
    float4* mp = (float4*)(M + (size_t)g * D + l * 8);
    mp[0] = a0;
    mp[1] = a1;
}

// BIG-WS PATH kernel 2: dense GEMM, no LDS, no barriers. Block = 64 dsts.
// A-frags straight from M (fp32 -> bf16 hi/lo in-register), B from Wt.
__global__ void __launch_bounds__(256, 4)
gemm_kernel(const float* __restrict__ x, const float* __restrict__ M,
            const ushort_t* __restrict__ WtH, const ushort_t* __restrict__ WtL,
            const float* __restrict__ bias, float* __restrict__ out) {
    int tid = threadIdx.x;
    int lane = tid & 63;
    int wave = tid >> 6;
    int mrow = lane & 15;
    int kg = lane >> 4;
    int n0 = blockIdx.x * 64;
    int row = n0 + wave * 16 + mrow;
    int rowc = row < N_NODES ? row : N_NODES - 1;  // clamp: OOB rows masked in epilogue

    f32x4 acc[8];
#pragma unroll
    for (int t = 0; t < 8; ++t) acc[t] = (f32x4){0.f, 0.f, 0.f, 0.f};

    for (int r = 0; r < 9; ++r) {
        const float* Arow = (r < 8) ? (M + ((size_t)r * N_NODES + rowc) * D)
                                    : (x + (size_t)rowc * D);
        const ushort_t* WH = WtH + ((size_t)r << 14);
        const ushort_t* WL = WtL + ((size_t)r << 14);
#pragma unroll
        for (int kstep = 0; kstep < 4; ++kstep) {
            int kofs = kstep * 32 + kg * 8;
            float4 f0 = *(const float4*)(Arow + kofs);
            float4 f1 = *(const float4*)(Arow + kofs + 4);
            float fv[8] = {f0.x, f0.y, f0.z, f0.w, f1.x, f1.y, f1.z, f1.w};
            short8 ah, al;
#pragma unroll
            for (int j = 0; j < 8; ++j) {
                float f = fv[j];
                ushort_t hb = f2bf(f);
                ah[j] = (short)hb;
                al[j] = (short)f2bf(f - bf2f(hb));
            }
#pragma unroll
            for (int nt = 0; nt < 8; ++nt) {
                int col = nt * 16 + mrow;
                short8 bh = *(const short8*)&WH[(size_t)col * D + kofs];
                short8 bl = *(const short8*)&WL[(size_t)col * D + kofs];
                acc[nt] = __builtin_amdgcn_mfma_f32_16x16x32_bf16(ah, bh, acc[nt], 0, 0, 0);
                acc[nt] = __builtin_amdgcn_mfma_f32_16x16x32_bf16(ah, bl, acc[nt], 0, 0, 0);
                acc[nt] = __builtin_amdgcn_mfma_f32_16x16x32_bf16(al, bh, acc[nt], 0, 0, 0);
            }
        }
    }

    // epilogue: D layout col=lane&15, row=(lane>>4)*4+j (verified rounds 5-7)
#pragma unroll
    for (int nt = 0; nt < 8; ++nt) {
        int col = nt * 16 + mrow;
        float bb = bias[col];
#pragma unroll
        for (int j = 0; j < 4; ++j) {
            int nn = n0 + wave * 16 + kg * 4 + j;
            if (nn < N_NODES) {
                float v = acc[nt][j] + bb;
                out[(size_t)nn * D + col] = v > 0.f ? v : 0.f;
            }
        }
    }
}

// FALLBACK (small ws): round-7 fused kernel, unchanged.
__global__ void __launch_bounds__(256, 4)
fused_kernel(const float* __restrict__ x,
             const ushort_t* __restrict__ WtH, const ushort_t* __restrict__ WtL,
             const float* __restrict__ bias, const int* __restrict__ ends,
             const uint_t* __restrict__ bucket, float* __restrict__ out) {
    __shared__ float At[64][132];
    __shared__ float sinv[64];
    __shared__ int sEnd[64];
    __shared__ float bs[128];
    __shared__ int sBase;

    int tid = threadIdx.x;
    int lane = tid & 63;
    int wave = tid >> 6;
    int mrow = lane & 15;
    int kg = lane >> 4;
    int n0 = blockIdx.x * 64;
    if (tid < 128) bs[tid] = bias[tid];

    f32x4 acc[8];
#pragma unroll
    for (int t = 0; t < 8; ++t) acc[t] = (f32x4){0.f, 0.f, 0.f, 0.f};

    for (int r = 0; r < R; ++r) {
        __syncthreads();
#pragma unroll
        for (int u = 0; u < 33; ++u) ((float*)At)[tid + u * 256] = 0.f;
        if (tid < 64) {
            int n = n0 + tid;
            if (n > N_NODES - 1) n = N_NODES - 1;
            int key = r * N_NODES + n;
            int e1 = ends[key];
            int e0 = (key == 0) ? 0 : ends[key - 1];
            int c = e1 - e0;
            sinv[tid] = (c > 0) ? 1.0f / (float)c : 0.0f;
            sEnd[tid] = e1;
            if (tid == 0) sBase = e0;
        }
        __syncthreads();
        int base = sBase;
        int nItems = (sEnd[63] - base) << 5;

        for (int i = tid; i < nItems; i += 256) {
            uint_t v = bucket[base + (i >> 5)];
            int src = v & 0x1FFFF;
            int dl = (v >> 17) & 63;
            int ch = i & 31;
            float4 xv = *(const float4*)(x + (size_t)src * D + ch * 4);
            float* rp = &At[dl][ch * 4];
            atomicAdd(rp + 0, xv.x);
            atomicAdd(rp + 1, xv.y);
            atomicAdd(rp + 2, xv.z);
            atomicAdd(rp + 3, xv.w);
        }
        __syncthreads();

        const ushort_t* WH = WtH + ((size_t)r << 14);
        const ushort_t* WL = WtL + ((size_t)r << 14);
        int row = wave * 16 + mrow;
        float iv = sinv[row];
#pragma unroll
        for (int kstep = 0; kstep < 4; ++kstep) {
            int kofs = kstep * 32 + kg * 8;
            float4 f0 = *(const float4*)&At[row][kofs];
            float4 f1 = *(const float4*)&At[row][kofs + 4];
            float fv[8] = {f0.x, f0.y, f0.z, f0.w, f1.x, f1.y, f1.z, f1.w};
            short8 ah, al;
#pragma unroll
            for (int j = 0; j < 8; ++j) {
                float f = fv[j] * iv;
                ushort_t hb = f2bf(f);
                ah[j] = (short)hb;
                al[j] = (short)f2bf(f - bf2f(hb));
            }
#pragma unroll
            for (int nt = 0; nt < 8; ++nt) {
                int col = nt * 16 + mrow;
                short8 bh = *(const short8*)&WH[(size_t)col * D + kofs];
                short8 bl = *(const short8*)&WL[(size_t)col * D + kofs];
                acc[nt] = __builtin_amdgcn_mfma_f32_16x16x32_bf16(ah, bh, acc[nt], 0, 0, 0);
                acc[nt] = __builtin_amdgcn_mfma_f32_16x16x32_bf16(ah, bl, acc[nt], 0, 0, 0);
                acc[nt] = __builtin_amdgcn_mfma_f32_16x16x32_bf16(al, bh, acc[nt], 0, 0, 0);
            }
        }
    }

    {
        const ushort_t* WH = WtH + ((size_t)8 << 14);
        const ushort_t* WL = WtL + ((size_t)8 << 14);
        int n = n0 + wave * 16 + mrow;
#pragma unroll
        for (int kstep = 0; kstep < 4; ++kstep) {
            int kofs = kstep * 32 + kg * 8;
            float fv[8] = {0.f, 0.f, 0.f, 0.f, 0.f, 0.f, 0.f, 0.f};
            if (n < N_NODES) {
                const float4* xp = (const float4*)(x + (size_t)n * D + kofs);
                float4 f0 = xp[0], f1 = xp[1];
                fv[0] = f0.x; fv[1] = f0.y; fv[2] = f0.z; fv[3] = f0.w;
                fv[4] = f1.x; fv[5] = f1.y; fv[6] = f1.z; fv[7] = f1.w;
            }
            short8 ah, al;
#pragma unroll
            for (int j = 0; j < 8; ++j) {
                float f = fv[j];
                ushort_t hb = f2bf(f);
                ah[j] = (short)hb;
                al[j] = (short)f2bf(f - bf2f(hb));
            }
#pragma unroll
            for (int nt = 0; nt < 8; ++nt) {
                int col = nt * 16 + mrow;
                short8 bh = *(const short8*)&WH[(size_t)col * D + kofs];
                short8 bl = *(const short8*)&WL[(size_t)col * D + kofs];
                acc[nt] = __builtin_amdgcn_mfma_f32_16x16x32_bf16(ah, bh, acc[nt], 0, 0, 0);
                acc[nt] = __builtin_amdgcn_mfma_f32_16x16x32_bf16(ah, bl, acc[nt], 0, 0, 0);
                acc[nt] = __builtin_amdgcn_mfma_f32_16x16x32_bf16(al, bh, acc[nt], 0, 0, 0);
            }
        }
    }

#pragma unroll
    for (int nt = 0; nt < 8; ++nt) {
        int col = nt * 16 + mrow;
        float bb = bs[col];
#pragma unroll
        for (int j = 0; j < 4; ++j) {
            int nn = n0 + wave * 16 + kg * 4 + j;
            if (nn < N_NODES) {
                float v = acc[nt][j] + bb;
                out[(size_t)nn * D + col] = v > 0.f ? v : 0.f;
            }
        }
    }
}

extern "C" void kernel_launch(void* const* d_in, const int* in_sizes, int n_in,
                              void* d_out, int out_size, void* d_ws, size_t ws_size,
                              hipStream_t stream) {
    const float* x     = (const float*)d_in[0];
    const int*   ei    = (const int*)d_in[1];
    const int*   et    = (const int*)d_in[2];
    const float* W     = (const float*)d_in[3];
    const float* Wroot = (const float*)d_in[4];
    const float* b     = (const float*)d_in[5];
    float* out = (float*)d_out;
    int* ws = (int*)d_ws;
    int* off = ws;                                   // NR ints
    uint_t* bucket = (uint_t*)(ws + NR);             // E packed words
    ushort_t* WtH = (ushort_t*)(ws + NR + E_EDGES);  // 9*16384 ushorts
    ushort_t* WtL = WtH + 9 * 16384;
    float* M = (float*)((char*)d_ws + FIXED_WS_BYTES);  // NR*D fp32 (big path)

    hipMemsetAsync(d_ws, 0, (size_t)NR * sizeof(int), stream);

    count_kernel<<<(E_EDGES + 255) / 256, 256, 0, stream>>>(ei, et, off);
    wt_kernel<<<9, 256, 0, stream>>>(W, Wroot, WtH, WtL);
    scan1_kernel<<<SCAN_BLOCKS, 256, 0, stream>>>(off, (int*)bucket);
    scan2_kernel<<<1, 512, 0, stream>>>((int*)bucket);
    scan3_kernel<<<SCAN_BLOCKS, 256, 0, stream>>>(off, (int*)bucket);
    bucket_kernel<<<(E_EDGES + 255) / 256, 256, 0, stream>>>(ei, et, off, bucket);

    if (ws_size >= BIG_WS_BYTES) {
        mean_kernel<<<NR / 16, 256, 0, stream>>>(x, off, bucket, M);
        gemm_kernel<<<(N_NODES + 63) / 64, 256, 0, stream>>>(x, M, WtH, WtL, b, out);
    } else {
        fused_kernel<<<(N_NODES + 63) / 64, 256, 0, stream>>>(x, WtH, WtL, b, off,
                                                              bucket, out);
    }
}

// Round 9
// 406.836 us; speedup vs baseline: 1.7442x; 1.1107x over previous
//
#include <hip/hip_runtime.h>

#define N_NODES 50000
#define D 128
#define R 8
#define E_EDGES 600000
#define NR (N_NODES * R)                 // 400000 (rel,dst) keys: key = r*N + dst
#define SCAN_BLOCKS ((NR + 1023) / 1024) // 391

typedef unsigned short ushort_t;
typedef unsigned int uint_t;
typedef __attribute__((ext_vector_type(8))) short short8;
typedef __attribute__((ext_vector_type(8))) ushort_t ushort8;
typedef __attribute__((ext_vector_type(4))) float f32x4;

// ws layout: [0,NR) int counts->offsets->ends ; [NR,NR+E) packed bucket ;
// WtH (9*128*128 ushort), WtL (same)  => 4,589,824 B ; then (big-ws path only)
// M = NR*D packed-uint32 means (hi bf16 <<16 | lo bf16), 204.8 MB.
#define FIXED_WS_BYTES 4589824
#define BIG_WS_BYTES (FIXED_WS_BYTES + (size_t)NR * D * 4)

static __device__ __forceinline__ ushort_t f2bf(float f) {
    uint_t u = __float_as_uint(f);
    uint_t r = u + 0x7fffu + ((u >> 16) & 1u);
    return (ushort_t)(r >> 16);
}
static __device__ __forceinline__ float bf2f(ushort_t h) {
    return __uint_as_float(((uint_t)h) << 16);
}

__global__ void __launch_bounds__(256)
count_kernel(const int* __restrict__ ei, const int* __restrict__ et,
             int* __restrict__ cnt) {
    int e = blockIdx.x * 256 + threadIdx.x;
    if (e < E_EDGES) {
        int dst = ei[E_EDGES + e];
        int r = et[e];
        atomicAdd(&cnt[r * N_NODES + dst], 1);
    }
}

__global__ void __launch_bounds__(256)
scan1_kernel(int* __restrict__ off, int* __restrict__ part) {
    __shared__ int wsum[4];
    int tid = threadIdx.x, lane = tid & 63, wid = tid >> 6;
    int base = blockIdx.x * 1024 + tid * 4;
    int c0 = 0, c1 = 0, c2 = 0, c3 = 0;
    if (base + 0 < NR) c0 = off[base + 0];
    if (base + 1 < NR) c1 = off[base + 1];
    if (base + 2 < NR) c2 = off[base + 2];
    if (base + 3 < NR) c3 = off[base + 3];
    int ts = c0 + c1 + c2 + c3;
    int v = ts;
#pragma unroll
    for (int o = 1; o < 64; o <<= 1) {
        int u = __shfl_up(v, o, 64);
        if (lane >= o) v += u;
    }
    if (lane == 63) wsum[wid] = v;
    __syncthreads();
    int wbase = 0;
#pragma unroll
    for (int w = 0; w < 4; ++w)
        if (w < wid) wbase += wsum[w];
    int excl = wbase + v - ts;
    if (base + 0 < NR) off[base + 0] = excl;
    if (base + 1 < NR) off[base + 1] = excl + c0;
    if (base + 2 < NR) off[base + 2] = excl + c0 + c1;
    if (base + 3 < NR) off[base + 3] = excl + c0 + c1 + c2;
    if (tid == 0) part[blockIdx.x] = wsum[0] + wsum[1] + wsum[2] + wsum[3];
}

__global__ void __launch_bounds__(512)
scan2_kernel(int* __restrict__ part) {
    __shared__ int sp[SCAN_BLOCKS];
    int tid = threadIdx.x;
    if (tid < SCAN_BLOCKS) sp[tid] = part[tid];
    __syncthreads();
    if (tid == 0) {
        int acc = 0;
        for (int i = 0; i < SCAN_BLOCKS; ++i) { int t = sp[i]; sp[i] = acc; acc += t; }
    }
    __syncthreads();
    if (tid < SCAN_BLOCKS) part[tid] = sp[tid];
}

__global__ void __launch_bounds__(256)
scan3_kernel(int* __restrict__ off, const int* __restrict__ part) {
    int p = part[blockIdx.x];
    int base = blockIdx.x * 1024 + threadIdx.x * 4;
#pragma unroll
    for (int i = 0; i < 4; ++i)
        if (base + i < NR) off[base + i] += p;
}

// Packed (src | dst_local<<17 | rel<<23) into (rel,dst)-sorted bucket.
__global__ void __launch_bounds__(256)
bucket_kernel(const int* __restrict__ ei, const int* __restrict__ et,
              int* __restrict__ off, uint_t* __restrict__ bucket) {
    int e = blockIdx.x * 256 + threadIdx.x;
    if (e < E_EDGES) {
        int src = ei[e];
        int dst = ei[E_EDGES + e];
        int r = et[e];
        int key = r * N_NODES + dst;
        int pos = atomicAdd(&off[key], 1);
        bucket[pos] = (uint_t)src | ((uint_t)(dst & 63) << 17) | ((uint_t)r << 23);
    }
}

// One-time: W[r][k][col] fp32 -> Wt[r][col][k] bf16 hi/lo.
__global__ void __launch_bounds__(256)
wt_kernel(const float* __restrict__ W, const float* __restrict__ Wroot,
          ushort_t* __restrict__ WtH, ushort_t* __restrict__ WtL) {
    int r = blockIdx.x;
    const float* Wr = (r < 8) ? (W + ((size_t)r << 14)) : Wroot;
    __shared__ float T[32][129];
    int tid = threadIdx.x;
    for (int k0 = 0; k0 < D; k0 += 32) {
#pragma unroll
        for (int u = 0; u < 16; ++u) {
            int idx = tid + u * 256;
            T[idx >> 7][idx & 127] = Wr[(size_t)k0 * D + idx];
        }
        __syncthreads();
        int col = tid & 127, kh = tid >> 7;
        ushort8 h0, h1, l0, l1;
#pragma unroll
        for (int kk = 0; kk < 8; ++kk) {
            float f = T[kh * 16 + kk][col];
            ushort_t hb = f2bf(f);
            h0[kk] = hb; l0[kk] = f2bf(f - bf2f(hb));
        }
#pragma unroll
        for (int kk = 0; kk < 8; ++kk) {
            float f = T[kh * 16 + 8 + kk][col];
            ushort_t hb = f2bf(f);
            h1[kk] = hb; l1[kk] = f2bf(f - bf2f(hb));
        }
        size_t o = ((size_t)r << 14) + (size_t)col * D + k0 + kh * 16;
        *(ushort8*)&WtH[o] = h0; *(ushort8*)&WtH[o + 8] = h1;
        *(ushort8*)&WtL[o] = l0; *(ushort8*)&WtL[o + 8] = l1;
        __syncthreads();
    }
}

// BIG-WS kernel 1: one 16-lane group per (rel,dst) key; mean of x_src rows;
// output PACKED uint32 = (bf16_hi << 16) | bf16_lo. Coalesced, no atomics.
__global__ void __launch_bounds__(256)
mean_kernel(const float* __restrict__ x, const int* __restrict__ ends,
            const uint_t* __restrict__ bucket, uint_t* __restrict__ M) {
    int tid = threadIdx.x;
    int g = blockIdx.x * 16 + (tid >> 4);  // key index, grid covers NR exactly
    int l = tid & 15;
    int e1 = ends[g];
    int e0 = (g == 0) ? 0 : ends[g - 1];
    float a[8] = {0.f, 0.f, 0.f, 0.f, 0.f, 0.f, 0.f, 0.f};
    for (int p = e0; p < e1; ++p) {
        int src = bucket[p] & 0x1FFFF;
        const float4* xp = (const float4*)(x + (size_t)src * D + l * 8);
        float4 v0 = xp[0], v1 = xp[1];
        a[0] += v0.x; a[1] += v0.y; a[2] += v0.z; a[3] += v0.w;
        a[4] += v1.x; a[5] += v1.y; a[6] += v1.z; a[7] += v1.w;
    }
    float inv = (e1 > e0) ? 1.0f / (float)(e1 - e0) : 0.0f;
    uint_t pk[8];
#pragma unroll
    for (int j = 0; j < 8; ++j) {
        float f = a[j] * inv;
        ushort_t hb = f2bf(f);
        ushort_t lb = f2bf(f - bf2f(hb));
        pk[j] = ((uint_t)hb << 16) | (uint_t)lb;
    }
    uint4* mp = (uint4*)(M + (size_t)g * D + l * 8);
    mp[0] = (uint4){pk[0], pk[1], pk[2], pk[3]};
    mp[1] = (uint4){pk[4], pk[5], pk[6], pk[7]};
}

// BIG-WS kernel 2: dense GEMM. Block = 64 dsts, 4 waves x 16 rows.
// Per relation: B (WH+WL, 64KB) staged in LDS with XOR-16B swizzle
// (addr ^ ((addr>>4)&0x70)); global B-loads issued BEFORE the barrier so they
// overlap the previous relation's MFMA. A read from packed M (2-op unpack).
__global__ void __launch_bounds__(256, 2)
gemm_kernel(const float* __restrict__ x, const uint_t* __restrict__ M,
            const ushort_t* __restrict__ WtH, const ushort_t* __restrict__ WtL,
            const float* __restrict__ bias, float* __restrict__ out) {
    __shared__ ushort_t Bh[16384];  // [col][k] bf16 hi, swizzled, 32 KB
    __shared__ ushort_t Bl[16384];  // lo, 32 KB
    int tid = threadIdx.x;
    int lane = tid & 63;
    int wave = tid >> 6;
    int mrow = lane & 15;
    int kg = lane >> 4;
    int n0 = blockIdx.x * 64;
    int row = n0 + wave * 16 + mrow;
    int rowc = row < N_NODES ? row : N_NODES - 1;  // OOB masked in epilogue

    f32x4 acc[8];
#pragma unroll
    for (int t = 0; t < 8; ++t) acc[t] = (f32x4){0.f, 0.f, 0.f, 0.f};

    for (int r = 0; r < 9; ++r) {
        // ---- issue B_r global loads (overlap prev relation's MFMA) ----
        const char* sH = (const char*)(WtH + ((size_t)r << 14));
        const char* sL = (const char*)(WtL + ((size_t)r << 14));
        uint4 th[8], tl[8];
#pragma unroll
        for (int j = 0; j < 8; ++j) {
            int o = tid * 16 + j * 4096;
            th[j] = *(const uint4*)(sH + o);
            tl[j] = *(const uint4*)(sL + o);
        }
        __syncthreads();  // prev relation's MFMA done reading Bh/Bl
#pragma unroll
        for (int j = 0; j < 8; ++j) {
            int o = tid * 16 + j * 4096;
            int wb = o ^ ((o >> 4) & 0x70);
            *(uint4*)((char*)Bh + wb) = th[j];
            *(uint4*)((char*)Bl + wb) = tl[j];
        }
        __syncthreads();

        const uint_t* Ar = M + ((size_t)r * N_NODES + rowc) * D;  // r<8
        const float* Ax = x + (size_t)rowc * D;                   // r==8
#pragma unroll
        for (int kstep = 0; kstep < 4; ++kstep) {
            int kofs = kstep * 32 + kg * 8;
            short8 ah, al;
            if (r < 8) {
                uint4 m0 = *(const uint4*)(Ar + kofs);
                uint4 m1 = *(const uint4*)(Ar + kofs + 4);
                uint_t mv[8] = {m0.x, m0.y, m0.z, m0.w, m1.x, m1.y, m1.z, m1.w};
#pragma unroll
                for (int j = 0; j < 8; ++j) {
                    ah[j] = (short)(mv[j] >> 16);
                    al[j] = (short)(mv[j] & 0xFFFFu);
                }
            } else {
                float4 f0 = *(const float4*)(Ax + kofs);
                float4 f1 = *(const float4*)(Ax + kofs + 4);
                float fv[8] = {f0.x, f0.y, f0.z, f0.w, f1.x, f1.y, f1.z, f1.w};
#pragma unroll
                for (int j = 0; j < 8; ++j) {
                    ushort_t hb = f2bf(fv[j]);
                    ah[j] = (short)hb;
                    al[j] = (short)f2bf(fv[j] - bf2f(hb));
                }
            }
#pragma unroll
            for (int nt = 0; nt < 8; ++nt) {
                int col = nt * 16 + mrow;
                int rb = col * 256 + kstep * 64 + kg * 16;
                int rs = rb ^ ((rb >> 4) & 0x70);
                short8 bh = *(const short8*)((const char*)Bh + rs);
                short8 bl = *(const short8*)((const char*)Bl + rs);
                acc[nt] = __builtin_amdgcn_mfma_f32_16x16x32_bf16(ah, bh, acc[nt], 0, 0, 0);
                acc[nt] = __builtin_amdgcn_mfma_f32_16x16x32_bf16(ah, bl, acc[nt], 0, 0, 0);
                acc[nt] = __builtin_amdgcn_mfma_f32_16x16x32_bf16(al, bh, acc[nt], 0, 0, 0);
            }
        }
    }

    // epilogue: D layout col=lane&15, row=(lane>>4)*4+j (verified rounds 5-8)
#pragma unroll
    for (int nt = 0; nt < 8; ++nt) {
        int col = nt * 16 + mrow;
        float bb = bias[col];
#pragma unroll
        for (int j = 0; j < 4; ++j) {
            int nn = n0 + wave * 16 + kg * 4 + j;
            if (nn < N_NODES) {
                float v = acc[nt][j] + bb;
                out[(size_t)nn * D + col] = v > 0.f ? v : 0.f;
            }
        }
    }
}

// FALLBACK (small ws): round-7 fused kernel, unchanged.
__global__ void __launch_bounds__(256, 4)
fused_kernel(const float* __restrict__ x,
             const ushort_t* __restrict__ WtH, const ushort_t* __restrict__ WtL,
             const float* __restrict__ bias, const int* __restrict__ ends,
             const uint_t* __restrict__ bucket, float* __restrict__ out) {
    __shared__ float At[64][132];
    __shared__ float sinv[64];
    __shared__ int sEnd[64];
    __shared__ float bs[128];
    __shared__ int sBase;

    int tid = threadIdx.x;
    int lane = tid & 63;
    int wave = tid >> 6;
    int mrow = lane & 15;
    int kg = lane >> 4;
    int n0 = blockIdx.x * 64;
    if (tid < 128) bs[tid] = bias[tid];

    f32x4 acc[8];
#pragma unroll
    for (int t = 0; t < 8; ++t) acc[t] = (f32x4){0.f, 0.f, 0.f, 0.f};

    for (int r = 0; r < R; ++r) {
        __syncthreads();
#pragma unroll
        for (int u = 0; u < 33; ++u) ((float*)At)[tid + u * 256] = 0.f;
        if (tid < 64) {
            int n = n0 + tid;
            if (n > N_NODES - 1) n = N_NODES - 1;
            int key = r * N_NODES + n;
            int e1 = ends[key];
            int e0 = (key == 0) ? 0 : ends[key - 1];
            int c = e1 - e0;
            sinv[tid] = (c > 0) ? 1.0f / (float)c : 0.0f;
            sEnd[tid] = e1;
            if (tid == 0) sBase = e0;
        }
        __syncthreads();
        int base = sBase;
        int nItems = (sEnd[63] - base) << 5;

        for (int i = tid; i < nItems; i += 256) {
            uint_t v = bucket[base + (i >> 5)];
            int src = v & 0x1FFFF;
            int dl = (v >> 17) & 63;
            int ch = i & 31;
            float4 xv = *(const float4*)(x + (size_t)src * D + ch * 4);
            float* rp = &At[dl][ch * 4];
            atomicAdd(rp + 0, xv.x);
            atomicAdd(rp + 1, xv.y);
            atomicAdd(rp + 2, xv.z);
            atomicAdd(rp + 3, xv.w);
        }
        __syncthreads();

        const ushort_t* WH = WtH + ((size_t)r << 14);
        const ushort_t* WL = WtL + ((size_t)r << 14);
        int rw = wave * 16 + mrow;
        float iv = sinv[rw];
#pragma unroll
        for (int kstep = 0; kstep < 4; ++kstep) {
            int kofs = kstep * 32 + kg * 8;
            float4 f0 = *(const float4*)&At[rw][kofs];
            float4 f1 = *(const float4*)&At[rw][kofs + 4];
            float fv[8] = {f0.x, f0.y, f0.z, f0.w, f1.x, f1.y, f1.z, f1.w};
            short8 ah, al;
#pragma unroll
            for (int j = 0; j < 8; ++j) {
                float f = fv[j] * iv;
                ushort_t hb = f2bf(f);
                ah[j] = (short)hb;
                al[j] = (short)f2bf(f - bf2f(hb));
            }
#pragma unroll
            for (int nt = 0; nt < 8; ++nt) {
                int col = nt * 16 + mrow;
                short8 bh = *(const short8*)&WH[(size_t)col * D + kofs];
                short8 bl = *(const short8*)&WL[(size_t)col * D + kofs];
                acc[nt] = __builtin_amdgcn_mfma_f32_16x16x32_bf16(ah, bh, acc[nt], 0, 0, 0);
                acc[nt] = __builtin_amdgcn_mfma_f32_16x16x32_bf16(ah, bl, acc[nt], 0, 0, 0);
                acc[nt] = __builtin_amdgcn_mfma_f32_16x16x32_bf16(al, bh, acc[nt], 0, 0, 0);
            }
        }
    }

    {
        const ushort_t* WH = WtH + ((size_t)8 << 14);
        const ushort_t* WL = WtL + ((size_t)8 << 14);
        int n = n0 + wave * 16 + mrow;
#pragma unroll
        for (int kstep = 0; kstep < 4; ++kstep) {
            int kofs = kstep * 32 + kg * 8;
            float fv[8] = {0.f, 0.f, 0.f, 0.f, 0.f, 0.f, 0.f, 0.f};
            if (n < N_NODES) {
                const float4* xp = (const float4*)(x + (size_t)n * D + kofs);
                float4 f0 = xp[0], f1 = xp[1];
                fv[0] = f0.x; fv[1] = f0.y; fv[2] = f0.z; fv[3] = f0.w;
                fv[4] = f1.x; fv[5] = f1.y; fv[6] = f1.z; fv[7] = f1.w;
            }
            short8 ah, al;
#pragma unroll
            for (int j = 0; j < 8; ++j) {
                float f = fv[j];
                ushort_t hb = f2bf(f);
                ah[j] = (short)hb;
                al[j] = (short)f2bf(f - bf2f(hb));
            }
#pragma unroll
            for (int nt = 0; nt < 8; ++nt) {
                int col = nt * 16 + mrow;
                short8 bh = *(const short8*)&WH[(size_t)col * D + kofs];
                short8 bl = *(const short8*)&WL[(size_t)col * D + kofs];
                acc[nt] = __builtin_amdgcn_mfma_f32_16x16x32_bf16(ah, bh, acc[nt], 0, 0, 0);
                acc[nt] = __builtin_amdgcn_mfma_f32_16x16x32_bf16(ah, bl, acc[nt], 0, 0, 0);
                acc[nt] = __builtin_amdgcn_mfma_f32_16x16x32_bf16(al, bh, acc[nt], 0, 0, 0);
            }
        }
    }

#pragma unroll
    for (int nt = 0; nt < 8; ++nt) {
        int col = nt * 16 + mrow;
        float bb = bs[col];
#pragma unroll
        for (int j = 0; j < 4; ++j) {
            int nn = n0 + wave * 16 + kg * 4 + j;
            if (nn < N_NODES) {
                float v = acc[nt][j] + bb;
                out[(size_t)nn * D + col] = v > 0.f ? v : 0.f;
            }
        }
    }
}

extern "C" void kernel_launch(void* const* d_in, const int* in_sizes, int n_in,
                              void* d_out, int out_size, void* d_ws, size_t ws_size,
                              hipStream_t stream) {
    const float* x     = (const float*)d_in[0];
    const int*   ei    = (const int*)d_in[1];
    const int*   et    = (const int*)d_in[2];
    const float* W     = (const float*)d_in[3];
    const float* Wroot = (const float*)d_in[4];
    const float* b     = (const float*)d_in[5];
    float* out = (float*)d_out;
    int* ws = (int*)d_ws;
    int* off = ws;                                   // NR ints
    uint_t* bucket = (uint_t*)(ws + NR);             // E packed words
    ushort_t* WtH = (ushort_t*)(ws + NR + E_EDGES);  // 9*16384 ushorts
    ushort_t* WtL = WtH + 9 * 16384;
    uint_t* M = (uint_t*)((char*)d_ws + FIXED_WS_BYTES);  // NR*D packed (big path)

    hipMemsetAsync(d_ws, 0, (size_t)NR * sizeof(int), stream);

    count_kernel<<<(E_EDGES + 255) / 256, 256, 0, stream>>>(ei, et, off);
    wt_kernel<<<9, 256, 0, stream>>>(W, Wroot, WtH, WtL);
    scan1_kernel<<<SCAN_BLOCKS, 256, 0, stream>>>(off, (int*)bucket);
    scan2_kernel<<<1, 512, 0, stream>>>((int*)bucket);
    scan3_kernel<<<SCAN_BLOCKS, 256, 0, stream>>>(off, (int*)bucket);
    bucket_kernel<<<(E_EDGES + 255) / 256, 256, 0, stream>>>(ei, et, off, bucket);

    if (ws_size >= BIG_WS_BYTES) {
        mean_kernel<<<NR / 16, 256, 0, stream>>>(x, off, bucket, M);
        gemm_kernel<<<(N_NODES + 63) / 64, 256, 0, stream>>>(x, M, WtH, WtL, b, out);
    } else {
        fused_kernel<<<(N_NODES + 63) / 64, 256, 0, stream>>>(x, WtH, WtL, b, off,
                                                              bucket, out);
    }
}

// Round 10
// 247.359 us; speedup vs baseline: 2.8686x; 1.6447x over previous
//
#include <hip/hip_runtime.h>

#define N_NODES 50000
#define D 128
#define R 8
#define E_EDGES 600000
#define NR (N_NODES * R)                 // 400000 (rel,dst) keys: key = r*N + dst
#define SCAN_BLOCKS ((NR + 1023) / 1024) // 391

typedef unsigned short ushort_t;
typedef unsigned int uint_t;
typedef __attribute__((ext_vector_type(8))) short short8;
typedef __attribute__((ext_vector_type(8))) ushort_t ushort8;
typedef __attribute__((ext_vector_type(4))) float f32x4;

// ws layout: [0,NR) int counts->offsets->ends ; [NR,NR+E) packed bucket ;
// WtH (9*128*128 ushort), WtL (same)  => 4,589,824 B ; then (big-ws path only)
// M = NR*D packed-uint32 means (hi bf16 <<16 | lo bf16), 204.8 MB.
#define FIXED_WS_BYTES 4589824
#define BIG_WS_BYTES (FIXED_WS_BYTES + (size_t)NR * D * 4)

static __device__ __forceinline__ ushort_t f2bf(float f) {
    uint_t u = __float_as_uint(f);
    uint_t r = u + 0x7fffu + ((u >> 16) & 1u);
    return (ushort_t)(r >> 16);
}
static __device__ __forceinline__ float bf2f(ushort_t h) {
    return __uint_as_float(((uint_t)h) << 16);
}

// Direct global->LDS DMA, 16B per lane. LDS dest = wave-uniform base + lane*16.
static __device__ __forceinline__ void gload_lds16(const void* g, void* l) {
    __builtin_amdgcn_global_load_lds(
        (const __attribute__((address_space(1))) unsigned int*)g,
        (__attribute__((address_space(3))) unsigned int*)l, 16, 0, 0);
}

__global__ void __launch_bounds__(256)
count_kernel(const int* __restrict__ ei, const int* __restrict__ et,
             int* __restrict__ cnt) {
    int e = blockIdx.x * 256 + threadIdx.x;
    if (e < E_EDGES) {
        int dst = ei[E_EDGES + e];
        int r = et[e];
        atomicAdd(&cnt[r * N_NODES + dst], 1);
    }
}

__global__ void __launch_bounds__(256)
scan1_kernel(int* __restrict__ off, int* __restrict__ part) {
    __shared__ int wsum[4];
    int tid = threadIdx.x, lane = tid & 63, wid = tid >> 6;
    int base = blockIdx.x * 1024 + tid * 4;
    int c0 = 0, c1 = 0, c2 = 0, c3 = 0;
    if (base + 0 < NR) c0 = off[base + 0];
    if (base + 1 < NR) c1 = off[base + 1];
    if (base + 2 < NR) c2 = off[base + 2];
    if (base + 3 < NR) c3 = off[base + 3];
    int ts = c0 + c1 + c2 + c3;
    int v = ts;
#pragma unroll
    for (int o = 1; o < 64; o <<= 1) {
        int u = __shfl_up(v, o, 64);
        if (lane >= o) v += u;
    }
    if (lane == 63) wsum[wid] = v;
    __syncthreads();
    int wbase = 0;
#pragma unroll
    for (int w = 0; w < 4; ++w)
        if (w < wid) wbase += wsum[w];
    int excl = wbase + v - ts;
    if (base + 0 < NR) off[base + 0] = excl;
    if (base + 1 < NR) off[base + 1] = excl + c0;
    if (base + 2 < NR) off[base + 2] = excl + c0 + c1;
    if (base + 3 < NR) off[base + 3] = excl + c0 + c1 + c2;
    if (tid == 0) part[blockIdx.x] = wsum[0] + wsum[1] + wsum[2] + wsum[3];
}

__global__ void __launch_bounds__(512)
scan2_kernel(int* __restrict__ part) {
    __shared__ int sp[SCAN_BLOCKS];
    int tid = threadIdx.x;
    if (tid < SCAN_BLOCKS) sp[tid] = part[tid];
    __syncthreads();
    if (tid == 0) {
        int acc = 0;
        for (int i = 0; i < SCAN_BLOCKS; ++i) { int t = sp[i]; sp[i] = acc; acc += t; }
    }
    __syncthreads();
    if (tid < SCAN_BLOCKS) part[tid] = sp[tid];
}

__global__ void __launch_bounds__(256)
scan3_kernel(int* __restrict__ off, const int* __restrict__ part) {
    int p = part[blockIdx.x];
    int base = blockIdx.x * 1024 + threadIdx.x * 4;
#pragma unroll
    for (int i = 0; i < 4; ++i)
        if (base + i < NR) off[base + i] += p;
}

// Packed (src | dst_local<<17 | rel<<23) into (rel,dst)-sorted bucket.
__global__ void __launch_bounds__(256)
bucket_kernel(const int* __restrict__ ei, const int* __restrict__ et,
              int* __restrict__ off, uint_t* __restrict__ bucket) {
    int e = blockIdx.x * 256 + threadIdx.x;
    if (e < E_EDGES) {
        int src = ei[e];
        int dst = ei[E_EDGES + e];
        int r = et[e];
        int key = r * N_NODES + dst;
        int pos = atomicAdd(&off[key], 1);
        bucket[pos] = (uint_t)src | ((uint_t)(dst & 63) << 17) | ((uint_t)r << 23);
    }
}

// One-time: W[r][k][col] fp32 -> Wt[r][col][k] bf16 hi/lo.
__global__ void __launch_bounds__(256)
wt_kernel(const float* __restrict__ W, const float* __restrict__ Wroot,
          ushort_t* __restrict__ WtH, ushort_t* __restrict__ WtL) {
    int r = blockIdx.x;
    const float* Wr = (r < 8) ? (W + ((size_t)r << 14)) : Wroot;
    __shared__ float T[32][129];
    int tid = threadIdx.x;
    for (int k0 = 0; k0 < D; k0 += 32) {
#pragma unroll
        for (int u = 0; u < 16; ++u) {
            int idx = tid + u * 256;
            T[idx >> 7][idx & 127] = Wr[(size_t)k0 * D + idx];
        }
        __syncthreads();
        int col = tid & 127, kh = tid >> 7;
        ushort8 h0, h1, l0, l1;
#pragma unroll
        for (int kk = 0; kk < 8; ++kk) {
            float f = T[kh * 16 + kk][col];
            ushort_t hb = f2bf(f);
            h0[kk] = hb; l0[kk] = f2bf(f - bf2f(hb));
        }
#pragma unroll
        for (int kk = 0; kk < 8; ++kk) {
            float f = T[kh * 16 + 8 + kk][col];
            ushort_t hb = f2bf(f);
            h1[kk] = hb; l1[kk] = f2bf(f - bf2f(hb));
        }
        size_t o = ((size_t)r << 14) + (size_t)col * D + k0 + kh * 16;
        *(ushort8*)&WtH[o] = h0; *(ushort8*)&WtH[o + 8] = h1;
        *(ushort8*)&WtL[o] = l0; *(ushort8*)&WtL[o + 8] = l1;
        __syncthreads();
    }
}

// BIG-WS kernel 1: one 16-lane group per (rel,dst) key; mean of x_src rows;
// output PACKED uint32 = (bf16_hi << 16) | bf16_lo. Coalesced, no atomics.
__global__ void __launch_bounds__(256)
mean_kernel(const float* __restrict__ x, const int* __restrict__ ends,
            const uint_t* __restrict__ bucket, uint_t* __restrict__ M) {
    int tid = threadIdx.x;
    int g = blockIdx.x * 16 + (tid >> 4);  // key index, grid covers NR exactly
    int l = tid & 15;
    int e1 = ends[g];
    int e0 = (g == 0) ? 0 : ends[g - 1];
    float a[8] = {0.f, 0.f, 0.f, 0.f, 0.f, 0.f, 0.f, 0.f};
    for (int p = e0; p < e1; ++p) {
        int src = bucket[p] & 0x1FFFF;
        const float4* xp = (const float4*)(x + (size_t)src * D + l * 8);
        float4 v0 = xp[0], v1 = xp[1];
        a[0] += v0.x; a[1] += v0.y; a[2] += v0.z; a[3] += v0.w;
        a[4] += v1.x; a[5] += v1.y; a[6] += v1.z; a[7] += v1.w;
    }
    float inv = (e1 > e0) ? 1.0f / (float)(e1 - e0) : 0.0f;
    uint_t pk[8];
#pragma unroll
    for (int j = 0; j < 8; ++j) {
        float f = a[j] * inv;
        ushort_t hb = f2bf(f);
        ushort_t lb = f2bf(f - bf2f(hb));
        pk[j] = ((uint_t)hb << 16) | (uint_t)lb;
    }
    uint4* mp = (uint4*)(M + (size_t)g * D + l * 8);
    mp[0] = (uint4){pk[0], pk[1], pk[2], pk[3]};
    mp[1] = (uint4){pk[4], pk[5], pk[6], pk[7]};
}

// BIG-WS kernel 2: dense GEMM. Block = 64 dsts, 4 waves x 16 rows.
// Per relation: B (WH|WL, 64KB) staged via global_load_lds (no VGPR roundtrip,
// no spill). LDS dest LINEAR; XOR-16B swizzle applied to the GLOBAL SOURCE
// address (involution on bits 4-6), and again on the ds_read side -> net
// identity on data, conflict-free banks (m201 both-sides pattern).
__global__ void __launch_bounds__(256, 2)
gemm_kernel(const float* __restrict__ x, const uint_t* __restrict__ M,
            const ushort_t* __restrict__ WtH, const ushort_t* __restrict__ WtL,
            const float* __restrict__ bias, float* __restrict__ out) {
    __shared__ ushort_t Bc[32768];  // 64KB: [0,32KB)=Bh, [32KB,64KB)=Bl
    int tid = threadIdx.x;
    int lane = tid & 63;
    int wave = tid >> 6;
    int mrow = lane & 15;
    int kg = lane >> 4;
    int n0 = blockIdx.x * 64;
    int row = n0 + wave * 16 + mrow;
    int rowc = row < N_NODES ? row : N_NODES - 1;  // OOB masked in epilogue

    f32x4 acc[8];
#pragma unroll
    for (int t = 0; t < 8; ++t) acc[t] = (f32x4){0.f, 0.f, 0.f, 0.f};

    for (int r = 0; r < 9; ++r) {
        const char* sH = (const char*)(WtH + ((size_t)r << 14));
        const char* sL = (const char*)(WtL + ((size_t)r << 14));
        __syncthreads();  // prev relation's MFMA done reading Bc
        // stage 64KB: wave w owns chunks w*16..+15 (1KB each, lanes add l*16)
#pragma unroll
        for (int j = 0; j < 16; ++j) {
            int chunk = wave * 16 + j;
            int o = chunk * 1024 + lane * 16;   // linear LDS byte offset
            int ol = o & 32767;                 // offset within 32KB half
            int osw = ol ^ ((ol >> 4) & 0x70);  // pre-swizzled source
            const char* src = (o < 32768) ? (sH + osw) : (sL + osw);
            gload_lds16(src, (char*)Bc + chunk * 1024);
        }
        __syncthreads();  // drains vmcnt -> LDS staged

        const uint_t* Ar = M + ((size_t)r * N_NODES + rowc) * D;  // r<8
        const float* Ax = x + (size_t)rowc * D;                   // r==8
#pragma unroll
        for (int kstep = 0; kstep < 4; ++kstep) {
            int kofs = kstep * 32 + kg * 8;
            short8 ah, al;
            if (r < 8) {
                uint4 m0 = *(const uint4*)(Ar + kofs);
                uint4 m1 = *(const uint4*)(Ar + kofs + 4);
                uint_t mv[8] = {m0.x, m0.y, m0.z, m0.w, m1.x, m1.y, m1.z, m1.w};
#pragma unroll
                for (int j = 0; j < 8; ++j) {
                    ah[j] = (short)(mv[j] >> 16);
                    al[j] = (short)(mv[j] & 0xFFFFu);
                }
            } else {
                float4 f0 = *(const float4*)(Ax + kofs);
                float4 f1 = *(const float4*)(Ax + kofs + 4);
                float fv[8] = {f0.x, f0.y, f0.z, f0.w, f1.x, f1.y, f1.z, f1.w};
#pragma unroll
                for (int j = 0; j < 8; ++j) {
                    ushort_t hb = f2bf(fv[j]);
                    ah[j] = (short)hb;
                    al[j] = (short)f2bf(fv[j] - bf2f(hb));
                }
            }
#pragma unroll
            for (int nt = 0; nt < 8; ++nt) {
                int col = nt * 16 + mrow;
                int rb = col * 256 + kstep * 64 + kg * 16;  // logical byte in half
                int rs = rb ^ ((rb >> 4) & 0x70);           // swizzled LDS byte
                short8 bh = *(const short8*)((const char*)Bc + rs);
                short8 bl = *(const short8*)((const char*)Bc + 32768 + rs);
                acc[nt] = __builtin_amdgcn_mfma_f32_16x16x32_bf16(ah, bh, acc[nt], 0, 0, 0);
                acc[nt] = __builtin_amdgcn_mfma_f32_16x16x32_bf16(ah, bl, acc[nt], 0, 0, 0);
                acc[nt] = __builtin_amdgcn_mfma_f32_16x16x32_bf16(al, bh, acc[nt], 0, 0, 0);
            }
        }
    }

    // epilogue: D layout col=lane&15, row=(lane>>4)*4+j (verified rounds 5-9)
#pragma unroll
    for (int nt = 0; nt < 8; ++nt) {
        int col = nt * 16 + mrow;
        float bb = bias[col];
#pragma unroll
        for (int j = 0; j < 4; ++j) {
            int nn = n0 + wave * 16 + kg * 4 + j;
            if (nn < N_NODES) {
                float v = acc[nt][j] + bb;
                out[(size_t)nn * D + col] = v > 0.f ? v : 0.f;
            }
        }
    }
}

// FALLBACK (small ws): round-7 fused kernel, unchanged.
__global__ void __launch_bounds__(256, 4)
fused_kernel(const float* __restrict__ x,
             const ushort_t* __restrict__ WtH, const ushort_t* __restrict__ WtL,
             const float* __restrict__ bias, const int* __restrict__ ends,
             const uint_t* __restrict__ bucket, float* __restrict__ out) {
    __shared__ float At[64][132];
    __shared__ float sinv[64];
    __shared__ int sEnd[64];
    __shared__ float bs[128];
    __shared__ int sBase;

    int tid = threadIdx.x;
    int lane = tid & 63;
    int wave = tid >> 6;
    int mrow = lane & 15;
    int kg = lane >> 4;
    int n0 = blockIdx.x * 64;
    if (tid < 128) bs[tid] = bias[tid];

    f32x4 acc[8];
#pragma unroll
    for (int t = 0; t < 8; ++t) acc[t] = (f32x4){0.f, 0.f, 0.f, 0.f};

    for (int r = 0; r < R; ++r) {
        __syncthreads();
#pragma unroll
        for (int u = 0; u < 33; ++u) ((float*)At)[tid + u * 256] = 0.f;
        if (tid < 64) {
            int n = n0 + tid;
            if (n > N_NODES - 1) n = N_NODES - 1;
            int key = r * N_NODES + n;
            int e1 = ends[key];
            int e0 = (key == 0) ? 0 : ends[key - 1];
            int c = e1 - e0;
            sinv[tid] = (c > 0) ? 1.0f / (float)c : 0.0f;
            sEnd[tid] = e1;
            if (tid == 0) sBase = e0;
        }
        __syncthreads();
        int base = sBase;
        int nItems = (sEnd[63] - base) << 5;

        for (int i = tid; i < nItems; i += 256) {
            uint_t v = bucket[base + (i >> 5)];
            int src = v & 0x1FFFF;
            int dl = (v >> 17) & 63;
            int ch = i & 31;
            float4 xv = *(const float4*)(x + (size_t)src * D + ch * 4);
            float* rp = &At[dl][ch * 4];
            atomicAdd(rp + 0, xv.x);
            atomicAdd(rp + 1, xv.y);
            atomicAdd(rp + 2, xv.z);
            atomicAdd(rp + 3, xv.w);
        }
        __syncthreads();

        const ushort_t* WH = WtH + ((size_t)r << 14);
        const ushort_t* WL = WtL + ((size_t)r << 14);
        int rw = wave * 16 + mrow;
        float iv = sinv[rw];
#pragma unroll
        for (int kstep = 0; kstep < 4; ++kstep) {
            int kofs = kstep * 32 + kg * 8;
            float4 f0 = *(const float4*)&At[rw][kofs];
            float4 f1 = *(const float4*)&At[rw][kofs + 4];
            float fv[8] = {f0.x, f0.y, f0.z, f0.w, f1.x, f1.y, f1.z, f1.w};
            short8 ah, al;
#pragma unroll
            for (int j = 0; j < 8; ++j) {
                float f = fv[j] * iv;
                ushort_t hb = f2bf(f);
                ah[j] = (short)hb;
                al[j] = (short)f2bf(f - bf2f(hb));
            }
#pragma unroll
            for (int nt = 0; nt < 8; ++nt) {
                int col = nt * 16 + mrow;
                short8 bh = *(const short8*)&WH[(size_t)col * D + kofs];
                short8 bl = *(const short8*)&WL[(size_t)col * D + kofs];
                acc[nt] = __builtin_amdgcn_mfma_f32_16x16x32_bf16(ah, bh, acc[nt], 0, 0, 0);
                acc[nt] = __builtin_amdgcn_mfma_f32_16x16x32_bf16(ah, bl, acc[nt], 0, 0, 0);
                acc[nt] = __builtin_amdgcn_mfma_f32_16x16x32_bf16(al, bh, acc[nt], 0, 0, 0);
            }
        }
    }

    {
        const ushort_t* WH = WtH + ((size_t)8 << 14);
        const ushort_t* WL = WtL + ((size_t)8 << 14);
        int n = n0 + wave * 16 + mrow;
#pragma unroll
        for (int kstep = 0; kstep < 4; ++kstep) {
            int kofs = kstep * 32 + kg * 8;
            float fv[8] = {0.f, 0.f, 0.f, 0.f, 0.f, 0.f, 0.f, 0.f};
            if (n < N_NODES) {
                const float4* xp = (const float4*)(x + (size_t)n * D + kofs);
                float4 f0 = xp[0], f1 = xp[1];
                fv[0] = f0.x; fv[1] = f0.y; fv[2] = f0.z; fv[3] = f0.w;
                fv[4] = f1.x; fv[5] = f1.y; fv[6] = f1.z; fv[7] = f1.w;
            }
            short8 ah, al;
#pragma unroll
            for (int j = 0; j < 8; ++j) {
                float f = fv[j];
                ushort_t hb = f2bf(f);
                ah[j] = (short)hb;
                al[j] = (short)f2bf(f - bf2f(hb));
            }
#pragma unroll
            for (int nt = 0; nt < 8; ++nt) {
                int col = nt * 16 + mrow;
                short8 bh = *(const short8*)&WH[(size_t)col * D + kofs];
                short8 bl = *(const short8*)&WL[(size_t)col * D + kofs];
                acc[nt] = __builtin_amdgcn_mfma_f32_16x16x32_bf16(ah, bh, acc[nt], 0, 0, 0);
                acc[nt] = __builtin_amdgcn_mfma_f32_16x16x32_bf16(ah, bl, acc[nt], 0, 0, 0);
                acc[nt] = __builtin_amdgcn_mfma_f32_16x16x32_bf16(al, bh, acc[nt], 0, 0, 0);
            }
        }
    }

#pragma unroll
    for (int nt = 0; nt < 8; ++nt) {
        int col = nt * 16 + mrow;
        float bb = bs[col];
#pragma unroll
        for (int j = 0; j < 4; ++j) {
            int nn = n0 + wave * 16 + kg * 4 + j;
            if (nn < N_NODES) {
                float v = acc[nt][j] + bb;
                out[(size_t)nn * D + col] = v > 0.f ? v : 0.f;
            }
        }
    }
}

extern "C" void kernel_launch(void* const* d_in, const int* in_sizes, int n_in,
                              void* d_out, int out_size, void* d_ws, size_t ws_size,
                              hipStream_t stream) {
    const float* x     = (const float*)d_in[0];
    const int*   ei    = (const int*)d_in[1];
    const int*   et    = (const int*)d_in[2];
    const float* W     = (const float*)d_in[3];
    const float* Wroot = (const float*)d_in[4];
    const float* b     = (const float*)d_in[5];
    float* out = (float*)d_out;
    int* ws = (int*)d_ws;
    int* off = ws;                                   // NR ints
    uint_t* bucket = (uint_t*)(ws + NR);             // E packed words
    ushort_t* WtH = (ushort_t*)(ws + NR + E_EDGES);  // 9*16384 ushorts
    ushort_t* WtL = WtH + 9 * 16384;
    uint_t* M = (uint_t*)((char*)d_ws + FIXED_WS_BYTES);  // NR*D packed (big path)

    hipMemsetAsync(d_ws, 0, (size_t)NR * sizeof(int), stream);

    count_kernel<<<(E_EDGES + 255) / 256, 256, 0, stream>>>(ei, et, off);
    wt_kernel<<<9, 256, 0, stream>>>(W, Wroot, WtH, WtL);
    scan1_kernel<<<SCAN_BLOCKS, 256, 0, stream>>>(off, (int*)bucket);
    scan2_kernel<<<1, 512, 0, stream>>>((int*)bucket);
    scan3_kernel<<<SCAN_BLOCKS, 256, 0, stream>>>(off, (int*)bucket);
    bucket_kernel<<<(E_EDGES + 255) / 256, 256, 0, stream>>>(ei, et, off, bucket);

    if (ws_size >= BIG_WS_BYTES) {
        mean_kernel<<<NR / 16, 256, 0, stream>>>(x, off, bucket, M);
        gemm_kernel<<<(N_NODES + 63) / 64, 256, 0, stream>>>(x, M, WtH, WtL, b, out);
    } else {
        fused_kernel<<<(N_NODES + 63) / 64, 256, 0, stream>>>(x, WtH, WtL, b, off,
                                                              bucket, out);
    }
}

// Round 11
// 190.191 us; speedup vs baseline: 3.7309x; 1.3006x over previous
//
#include <hip/hip_runtime.h>

#define N_NODES 50000
#define D 128
#define R 8
#define E_EDGES 600000
#define NR (N_NODES * R)                 // 400000 (rel,dst) keys: key = r*N + dst
#define SCAN_BLOCKS ((NR + 1023) / 1024) // 391

typedef unsigned short ushort_t;
typedef unsigned int uint_t;
typedef __attribute__((ext_vector_type(8))) short short8;
typedef __attribute__((ext_vector_type(8))) ushort_t ushort8;
typedef __attribute__((ext_vector_type(4))) float f32x4;

// ws layout: [0,NR) int counts->offsets->ends ; [NR,NR+E) packed bucket ;
// WtH (9*128*128 ushort), WtL (same) => 4,589,824 B ; then (big-ws path only)
// Mh = NR*D bf16-hi means (102.4 MB). A-lo plane dropped: adds ~0.008 max err,
// well under the 0.03125 tolerance (B stays hi/lo full precision).
#define FIXED_WS_BYTES 4589824
#define BIG_WS_BYTES (FIXED_WS_BYTES + (size_t)NR * D * 2)

static __device__ __forceinline__ ushort_t f2bf(float f) {
    uint_t u = __float_as_uint(f);
    uint_t r = u + 0x7fffu + ((u >> 16) & 1u);
    return (ushort_t)(r >> 16);
}
static __device__ __forceinline__ float bf2f(ushort_t h) {
    return __uint_as_float(((uint_t)h) << 16);
}

// Direct global->LDS DMA, 16B per lane. LDS dest = wave-uniform base + lane*16.
static __device__ __forceinline__ void gload_lds16(const void* g, void* l) {
    __builtin_amdgcn_global_load_lds(
        (const __attribute__((address_space(1))) unsigned int*)g,
        (__attribute__((address_space(3))) unsigned int*)l, 16, 0, 0);
}

__global__ void __launch_bounds__(256)
count_kernel(const int* __restrict__ ei, const int* __restrict__ et,
             int* __restrict__ cnt) {
    int e = blockIdx.x * 256 + threadIdx.x;
    if (e < E_EDGES) {
        int dst = ei[E_EDGES + e];
        int r = et[e];
        atomicAdd(&cnt[r * N_NODES + dst], 1);
    }
}

__global__ void __launch_bounds__(256)
scan1_kernel(int* __restrict__ off, int* __restrict__ part) {
    __shared__ int wsum[4];
    int tid = threadIdx.x, lane = tid & 63, wid = tid >> 6;
    int base = blockIdx.x * 1024 + tid * 4;
    int c0 = 0, c1 = 0, c2 = 0, c3 = 0;
    if (base + 0 < NR) c0 = off[base + 0];
    if (base + 1 < NR) c1 = off[base + 1];
    if (base + 2 < NR) c2 = off[base + 2];
    if (base + 3 < NR) c3 = off[base + 3];
    int ts = c0 + c1 + c2 + c3;
    int v = ts;
#pragma unroll
    for (int o = 1; o < 64; o <<= 1) {
        int u = __shfl_up(v, o, 64);
        if (lane >= o) v += u;
    }
    if (lane == 63) wsum[wid] = v;
    __syncthreads();
    int wbase = 0;
#pragma unroll
    for (int w = 0; w < 4; ++w)
        if (w < wid) wbase += wsum[w];
    int excl = wbase + v - ts;
    if (base + 0 < NR) off[base + 0] = excl;
    if (base + 1 < NR) off[base + 1] = excl + c0;
    if (base + 2 < NR) off[base + 2] = excl + c0 + c1;
    if (base + 3 < NR) off[base + 3] = excl + c0 + c1 + c2;
    if (tid == 0) part[blockIdx.x] = wsum[0] + wsum[1] + wsum[2] + wsum[3];
}

__global__ void __launch_bounds__(512)
scan2_kernel(int* __restrict__ part) {
    __shared__ int sp[SCAN_BLOCKS];
    int tid = threadIdx.x;
    if (tid < SCAN_BLOCKS) sp[tid] = part[tid];
    __syncthreads();
    if (tid == 0) {
        int acc = 0;
        for (int i = 0; i < SCAN_BLOCKS; ++i) { int t = sp[i]; sp[i] = acc; acc += t; }
    }
    __syncthreads();
    if (tid < SCAN_BLOCKS) part[tid] = sp[tid];
}

__global__ void __launch_bounds__(256)
scan3_kernel(int* __restrict__ off, const int* __restrict__ part) {
    int p = part[blockIdx.x];
    int base = blockIdx.x * 1024 + threadIdx.x * 4;
#pragma unroll
    for (int i = 0; i < 4; ++i)
        if (base + i < NR) off[base + i] += p;
}

// Packed (src | dst_local<<17 | rel<<23) into (rel,dst)-sorted bucket.
__global__ void __launch_bounds__(256)
bucket_kernel(const int* __restrict__ ei, const int* __restrict__ et,
              int* __restrict__ off, uint_t* __restrict__ bucket) {
    int e = blockIdx.x * 256 + threadIdx.x;
    if (e < E_EDGES) {
        int src = ei[e];
        int dst = ei[E_EDGES + e];
        int r = et[e];
        int key = r * N_NODES + dst;
        int pos = atomicAdd(&off[key], 1);
        bucket[pos] = (uint_t)src | ((uint_t)(dst & 63) << 17) | ((uint_t)r << 23);
    }
}

// One-time: W[r][k][col] fp32 -> Wt[r][col][k] bf16 hi/lo.
__global__ void __launch_bounds__(256)
wt_kernel(const float* __restrict__ W, const float* __restrict__ Wroot,
          ushort_t* __restrict__ WtH, ushort_t* __restrict__ WtL) {
    int r = blockIdx.x;
    const float* Wr = (r < 8) ? (W + ((size_t)r << 14)) : Wroot;
    __shared__ float T[32][129];
    int tid = threadIdx.x;
    for (int k0 = 0; k0 < D; k0 += 32) {
#pragma unroll
        for (int u = 0; u < 16; ++u) {
            int idx = tid + u * 256;
            T[idx >> 7][idx & 127] = Wr[(size_t)k0 * D + idx];
        }
        __syncthreads();
        int col = tid & 127, kh = tid >> 7;
        ushort8 h0, h1, l0, l1;
#pragma unroll
        for (int kk = 0; kk < 8; ++kk) {
            float f = T[kh * 16 + kk][col];
            ushort_t hb = f2bf(f);
            h0[kk] = hb; l0[kk] = f2bf(f - bf2f(hb));
        }
#pragma unroll
        for (int kk = 0; kk < 8; ++kk) {
            float f = T[kh * 16 + 8 + kk][col];
            ushort_t hb = f2bf(f);
            h1[kk] = hb; l1[kk] = f2bf(f - bf2f(hb));
        }
        size_t o = ((size_t)r << 14) + (size_t)col * D + k0 + kh * 16;
        *(ushort8*)&WtH[o] = h0; *(ushort8*)&WtH[o + 8] = h1;
        *(ushort8*)&WtL[o] = l0; *(ushort8*)&WtL[o + 8] = l1;
        __syncthreads();
    }
}

// BIG-WS kernel 1: one 16-lane group per (rel,dst) key; mean of x_src rows;
// output bf16-hi only (2B/elem). Coalesced 256B row writes, no atomics.
__global__ void __launch_bounds__(256)
mean_kernel(const float* __restrict__ x, const int* __restrict__ ends,
            const uint_t* __restrict__ bucket, ushort_t* __restrict__ Mh) {
    int tid = threadIdx.x;
    int g = blockIdx.x * 16 + (tid >> 4);  // key index, grid covers NR exactly
    int l = tid & 15;
    int e1 = ends[g];
    int e0 = (g == 0) ? 0 : ends[g - 1];
    float a[8] = {0.f, 0.f, 0.f, 0.f, 0.f, 0.f, 0.f, 0.f};
    for (int p = e0; p < e1; ++p) {
        int src = bucket[p] & 0x1FFFF;
        const float4* xp = (const float4*)(x + (size_t)src * D + l * 8);
        float4 v0 = xp[0], v1 = xp[1];
        a[0] += v0.x; a[1] += v0.y; a[2] += v0.z; a[3] += v0.w;
        a[4] += v1.x; a[5] += v1.y; a[6] += v1.z; a[7] += v1.w;
    }
    float inv = (e1 > e0) ? 1.0f / (float)(e1 - e0) : 0.0f;
    ushort8 h;
#pragma unroll
    for (int j = 0; j < 8; ++j) h[j] = f2bf(a[j] * inv);
    *(ushort8*)(Mh + (size_t)g * D + l * 8) = h;
}

// BIG-WS kernel 2: dense GEMM. Block = 128 dsts, 512 threads (8 waves x 16
// rows). Per relation: B (WH|WL, 64KB) staged via global_load_lds with
// source-side XOR-16B swizzle (involution, bits 4-6) undone on the ds_read
// side (m201 both-sides pattern). A = bf16-hi from Mh (direct ushort8 load,
// no unpack); 2 MFMA products (A*Bh + A*Bl).
__global__ void __launch_bounds__(512, 4)
gemm_kernel(const float* __restrict__ x, const ushort_t* __restrict__ Mh,
            const ushort_t* __restrict__ WtH, const ushort_t* __restrict__ WtL,
            const float* __restrict__ bias, float* __restrict__ out) {
    __shared__ ushort_t Bc[32768];  // 64KB: [0,32KB)=Bh, [32KB,64KB)=Bl
    int tid = threadIdx.x;
    int lane = tid & 63;
    int wave = tid >> 6;            // 0..7
    int mrow = lane & 15;
    int kg = lane >> 4;
    int n0 = blockIdx.x * 128;
    int row = n0 + wave * 16 + mrow;
    int rowc = row < N_NODES ? row : N_NODES - 1;  // OOB masked in epilogue

    f32x4 acc[8];
#pragma unroll
    for (int t = 0; t < 8; ++t) acc[t] = (f32x4){0.f, 0.f, 0.f, 0.f};

    for (int r = 0; r < 9; ++r) {
        const char* sH = (const char*)(WtH + ((size_t)r << 14));
        const char* sL = (const char*)(WtL + ((size_t)r << 14));
        __syncthreads();  // prev relation's MFMA done reading Bc
        // stage 64KB: 512 threads x 8 x 16B; wave w owns chunks w*8..+7 (1KB)
#pragma unroll
        for (int j = 0; j < 8; ++j) {
            int chunk = wave * 8 + j;
            int o = chunk * 1024 + lane * 16;   // linear LDS byte offset
            int ol = o & 32767;                 // offset within 32KB half
            int osw = ol ^ ((ol >> 4) & 0x70);  // pre-swizzled source
            const char* src = (o < 32768) ? (sH + osw) : (sL + osw);
            gload_lds16(src, (char*)Bc + chunk * 1024);
        }
        __syncthreads();  // drains vmcnt -> LDS staged

        const ushort_t* Ar = Mh + ((size_t)r * N_NODES + rowc) * D;  // r<8
        const float* Ax = x + (size_t)rowc * D;                      // r==8
#pragma unroll
        for (int kstep = 0; kstep < 4; ++kstep) {
            int kofs = kstep * 32 + kg * 8;
            short8 ah;
            if (r < 8) {
                ah = *(const short8*)(Ar + kofs);
            } else {
                float4 f0 = *(const float4*)(Ax + kofs);
                float4 f1 = *(const float4*)(Ax + kofs + 4);
                float fv[8] = {f0.x, f0.y, f0.z, f0.w, f1.x, f1.y, f1.z, f1.w};
#pragma unroll
                for (int j = 0; j < 8; ++j) ah[j] = (short)f2bf(fv[j]);
            }
#pragma unroll
            for (int nt = 0; nt < 8; ++nt) {
                int col = nt * 16 + mrow;
                int rb = col * 256 + kstep * 64 + kg * 16;  // logical byte in half
                int rs = rb ^ ((rb >> 4) & 0x70);           // swizzled LDS byte
                short8 bh = *(const short8*)((const char*)Bc + rs);
                short8 bl = *(const short8*)((const char*)Bc + 32768 + rs);
                acc[nt] = __builtin_amdgcn_mfma_f32_16x16x32_bf16(ah, bh, acc[nt], 0, 0, 0);
                acc[nt] = __builtin_amdgcn_mfma_f32_16x16x32_bf16(ah, bl, acc[nt], 0, 0, 0);
            }
        }
    }

    // epilogue: D layout col=lane&15, row=(lane>>4)*4+j (verified rounds 5-10)
#pragma unroll
    for (int nt = 0; nt < 8; ++nt) {
        int col = nt * 16 + mrow;
        float bb = bias[col];
#pragma unroll
        for (int j = 0; j < 4; ++j) {
            int nn = n0 + wave * 16 + kg * 4 + j;
            if (nn < N_NODES) {
                float v = acc[nt][j] + bb;
                out[(size_t)nn * D + col] = v > 0.f ? v : 0.f;
            }
        }
    }
}

// FALLBACK (small ws): round-7 fused kernel, unchanged.
__global__ void __launch_bounds__(256, 4)
fused_kernel(const float* __restrict__ x,
             const ushort_t* __restrict__ WtH, const ushort_t* __restrict__ WtL,
             const float* __restrict__ bias, const int* __restrict__ ends,
             const uint_t* __restrict__ bucket, float* __restrict__ out) {
    __shared__ float At[64][132];
    __shared__ float sinv[64];
    __shared__ int sEnd[64];
    __shared__ float bs[128];
    __shared__ int sBase;

    int tid = threadIdx.x;
    int lane = tid & 63;
    int wave = tid >> 6;
    int mrow = lane & 15;
    int kg = lane >> 4;
    int n0 = blockIdx.x * 64;
    if (tid < 128) bs[tid] = bias[tid];

    f32x4 acc[8];
#pragma unroll
    for (int t = 0; t < 8; ++t) acc[t] = (f32x4){0.f, 0.f, 0.f, 0.f};

    for (int r = 0; r < R; ++r) {
        __syncthreads();
#pragma unroll
        for (int u = 0; u < 33; ++u) ((float*)At)[tid + u * 256] = 0.f;
        if (tid < 64) {
            int n = n0 + tid;
            if (n > N_NODES - 1) n = N_NODES - 1;
            int key = r * N_NODES + n;
            int e1 = ends[key];
            int e0 = (key == 0) ? 0 : ends[key - 1];
            int c = e1 - e0;
            sinv[tid] = (c > 0) ? 1.0f / (float)c : 0.0f;
            sEnd[tid] = e1;
            if (tid == 0) sBase = e0;
        }
        __syncthreads();
        int base = sBase;
        int nItems = (sEnd[63] - base) << 5;

        for (int i = tid; i < nItems; i += 256) {
            uint_t v = bucket[base + (i >> 5)];
            int src = v & 0x1FFFF;
            int dl = (v >> 17) & 63;
            int ch = i & 31;
            float4 xv = *(const float4*)(x + (size_t)src * D + ch * 4);
            float* rp = &At[dl][ch * 4];
            atomicAdd(rp + 0, xv.x);
            atomicAdd(rp + 1, xv.y);
            atomicAdd(rp + 2, xv.z);
            atomicAdd(rp + 3, xv.w);
        }
        __syncthreads();

        const ushort_t* WH = WtH + ((size_t)r << 14);
        const ushort_t* WL = WtL + ((size_t)r << 14);
        int rw = wave * 16 + mrow;
        float iv = sinv[rw];
#pragma unroll
        for (int kstep = 0; kstep < 4; ++kstep) {
            int kofs = kstep * 32 + kg * 8;
            float4 f0 = *(const float4*)&At[rw][kofs];
            float4 f1 = *(const float4*)&At[rw][kofs + 4];
            float fv[8] = {f0.x, f0.y, f0.z, f0.w, f1.x, f1.y, f1.z, f1.w};
            short8 ah, al;
#pragma unroll
            for (int j = 0; j < 8; ++j) {
                float f = fv[j] * iv;
                ushort_t hb = f2bf(f);
                ah[j] = (short)hb;
                al[j] = (short)f2bf(f - bf2f(hb));
            }
#pragma unroll
            for (int nt = 0; nt < 8; ++nt) {
                int col = nt * 16 + mrow;
                short8 bh = *(const short8*)&WH[(size_t)col * D + kofs];
                short8 bl = *(const short8*)&WL[(size_t)col * D + kofs];
                acc[nt] = __builtin_amdgcn_mfma_f32_16x16x32_bf16(ah, bh, acc[nt], 0, 0, 0);
                acc[nt] = __builtin_amdgcn_mfma_f32_16x16x32_bf16(ah, bl, acc[nt], 0, 0, 0);
                acc[nt] = __builtin_amdgcn_mfma_f32_16x16x32_bf16(al, bh, acc[nt], 0, 0, 0);
            }
        }
    }

    {
        const ushort_t* WH = WtH + ((size_t)8 << 14);
        const ushort_t* WL = WtL + ((size_t)8 << 14);
        int n = n0 + wave * 16 + mrow;
#pragma unroll
        for (int kstep = 0; kstep < 4; ++kstep) {
            int kofs = kstep * 32 + kg * 8;
            float fv[8] = {0.f, 0.f, 0.f, 0.f, 0.f, 0.f, 0.f, 0.f};
            if (n < N_NODES) {
                const float4* xp = (const float4*)(x + (size_t)n * D + kofs);
                float4 f0 = xp[0], f1 = xp[1];
                fv[0] = f0.x; fv[1] = f0.y; fv[2] = f0.z; fv[3] = f0.w;
                fv[4] = f1.x; fv[5] = f1.y; fv[6] = f1.z; fv[7] = f1.w;
            }
            short8 ah, al;
#pragma unroll
            for (int j = 0; j < 8; ++j) {
                float f = fv[j];
                ushort_t hb = f2bf(f);
                ah[j] = (short)hb;
                al[j] = (short)f2bf(f - bf2f(hb));
            }
#pragma unroll
            for (int nt = 0; nt < 8; ++nt) {
                int col = nt * 16 + mrow;
                short8 bh = *(const short8*)&WH[(size_t)col * D + kofs];
                short8 bl = *(const short8*)&WL[(size_t)col * D + kofs];
                acc[nt] = __builtin_amdgcn_mfma_f32_16x16x32_bf16(ah, bh, acc[nt], 0, 0, 0);
                acc[nt] = __builtin_amdgcn_mfma_f32_16x16x32_bf16(ah, bl, acc[nt], 0, 0, 0);
                acc[nt] = __builtin_amdgcn_mfma_f32_16x16x32_bf16(al, bh, acc[nt], 0, 0, 0);
            }
        }
    }

#pragma unroll
    for (int nt = 0; nt < 8; ++nt) {
        int col = nt * 16 + mrow;
        float bb = bs[col];
#pragma unroll
        for (int j = 0; j < 4; ++j) {
            int nn = n0 + wave * 16 + kg * 4 + j;
            if (nn < N_NODES) {
                float v = acc[nt][j] + bb;
                out[(size_t)nn * D + col] = v > 0.f ? v : 0.f;
            }
        }
    }
}

extern "C" void kernel_launch(void* const* d_in, const int* in_sizes, int n_in,
                              void* d_out, int out_size, void* d_ws, size_t ws_size,
                              hipStream_t stream) {
    const float* x     = (const float*)d_in[0];
    const int*   ei    = (const int*)d_in[1];
    const int*   et    = (const int*)d_in[2];
    const float* W     = (const float*)d_in[3];
    const float* Wroot = (const float*)d_in[4];
    const float* b     = (const float*)d_in[5];
    float* out = (float*)d_out;
    int* ws = (int*)d_ws;
    int* off = ws;                                   // NR ints
    uint_t* bucket = (uint_t*)(ws + NR);             // E packed words
    ushort_t* WtH = (ushort_t*)(ws + NR + E_EDGES);  // 9*16384 ushorts
    ushort_t* WtL = WtH + 9 * 16384;
    ushort_t* Mh = (ushort_t*)((char*)d_ws + FIXED_WS_BYTES);  // NR*D bf16-hi

    hipMemsetAsync(d_ws, 0, (size_t)NR * sizeof(int), stream);

    count_kernel<<<(E_EDGES + 255) / 256, 256, 0, stream>>>(ei, et, off);
    wt_kernel<<<9, 256, 0, stream>>>(W, Wroot, WtH, WtL);
    scan1_kernel<<<SCAN_BLOCKS, 256, 0, stream>>>(off, (int*)bucket);
    scan2_kernel<<<1, 512, 0, stream>>>((int*)bucket);
    scan3_kernel<<<SCAN_BLOCKS, 256, 0, stream>>>(off, (int*)bucket);
    bucket_kernel<<<(E_EDGES + 255) / 256, 256, 0, stream>>>(ei, et, off, bucket);

    if (ws_size >= BIG_WS_BYTES) {
        mean_kernel<<<NR / 16, 256, 0, stream>>>(x, off, bucket, Mh);
        gemm_kernel<<<(N_NODES + 127) / 128, 512, 0, stream>>>(x, Mh, WtH, WtL, b, out);
    } else {
        fused_kernel<<<(N_NODES + 63) / 64, 256, 0, stream>>>(x, WtH, WtL, b, off,
                                                              bucket, out);
    }
}

// Round 12
// 152.126 us; speedup vs baseline: 4.6645x; 1.2502x over previous
//
#include <hip/hip_runtime.h>

#define N_NODES 50000
#define D 128
#define R 8
#define E_EDGES 600000
#define NR (N_NODES * R)                 // 400000 (rel,dst) keys: key = r*N + dst
#define SCAN_BLOCKS ((NR + 1023) / 1024) // 391

typedef unsigned short ushort_t;
typedef unsigned int uint_t;
typedef __attribute__((ext_vector_type(8))) short short8;
typedef __attribute__((ext_vector_type(8))) ushort_t ushort8;
typedef __attribute__((ext_vector_type(4))) float f32x4;

// ws layout (big path):
//   off    NR ints      (counts -> exclusive starts)
//   bucket E uints      (packed, (rel,dst)-sorted; scan partials alias head)
//   rank   E ints       (per-edge rank within its key, from count_kernel)
//   WtH    9*16384 ush  (W^T bf16 hi)   WtL same (lo)
//   Mh     NR*D ushort  (bf16-hi means, 102.4 MB)
#define FIXED_WS_BYTES ((size_t)(NR + E_EDGES + E_EDGES) * 4 + 2u * 9 * 16384 * 2)
#define BIG_WS_BYTES (FIXED_WS_BYTES + (size_t)NR * D * 2)

static __device__ __forceinline__ ushort_t f2bf(float f) {
    uint_t u = __float_as_uint(f);
    uint_t r = u + 0x7fffu + ((u >> 16) & 1u);
    return (ushort_t)(r >> 16);
}
static __device__ __forceinline__ float bf2f(ushort_t h) {
    return __uint_as_float(((uint_t)h) << 16);
}

// Direct global->LDS DMA, 16B per lane. LDS dest = wave-uniform base + lane*16.
static __device__ __forceinline__ void gload_lds16(const void* g, void* l) {
    __builtin_amdgcn_global_load_lds(
        (const __attribute__((address_space(1))) unsigned int*)g,
        (__attribute__((address_space(3))) unsigned int*)l, 16, 0, 0);
}

// count + per-edge rank (rank makes the later bucket scatter atomic-free)
__global__ void __launch_bounds__(256)
count_kernel(const int* __restrict__ ei, const int* __restrict__ et,
             int* __restrict__ cnt, int* __restrict__ rank) {
    int e = blockIdx.x * 256 + threadIdx.x;
    if (e < E_EDGES) {
        int dst = ei[E_EDGES + e];
        int r = et[e];
        rank[e] = atomicAdd(&cnt[r * N_NODES + dst], 1);
    }
}

__global__ void __launch_bounds__(256)
scan1_kernel(int* __restrict__ off, int* __restrict__ part) {
    __shared__ int wsum[4];
    int tid = threadIdx.x, lane = tid & 63, wid = tid >> 6;
    int base = blockIdx.x * 1024 + tid * 4;
    int c0 = 0, c1 = 0, c2 = 0, c3 = 0;
    if (base + 0 < NR) c0 = off[base + 0];
    if (base + 1 < NR) c1 = off[base + 1];
    if (base + 2 < NR) c2 = off[base + 2];
    if (base + 3 < NR) c3 = off[base + 3];
    int ts = c0 + c1 + c2 + c3;
    int v = ts;
#pragma unroll
    for (int o = 1; o < 64; o <<= 1) {
        int u = __shfl_up(v, o, 64);
        if (lane >= o) v += u;
    }
    if (lane == 63) wsum[wid] = v;
    __syncthreads();
    int wbase = 0;
#pragma unroll
    for (int w = 0; w < 4; ++w)
        if (w < wid) wbase += wsum[w];
    int excl = wbase + v - ts;
    if (base + 0 < NR) off[base + 0] = excl;
    if (base + 1 < NR) off[base + 1] = excl + c0;
    if (base + 2 < NR) off[base + 2] = excl + c0 + c1;
    if (base + 3 < NR) off[base + 3] = excl + c0 + c1 + c2;
    if (tid == 0) part[blockIdx.x] = wsum[0] + wsum[1] + wsum[2] + wsum[3];
}

// parallel exclusive scan of the 391 block partials
__global__ void __launch_bounds__(512)
scan2_kernel(int* __restrict__ part) {
    __shared__ int ws8[8];
    int t = threadIdx.x, lane = t & 63, w = t >> 6;
    int v = (t < SCAN_BLOCKS) ? part[t] : 0;
    int s = v;
#pragma unroll
    for (int o = 1; o < 64; o <<= 1) {
        int u = __shfl_up(s, o, 64);
        if (lane >= o) s += u;
    }
    if (lane == 63) ws8[w] = s;
    __syncthreads();
    int wb = 0;
#pragma unroll
    for (int i = 0; i < 8; ++i)
        if (i < w) wb += ws8[i];
    if (t < SCAN_BLOCKS) part[t] = wb + s - v;  // exclusive
}

__global__ void __launch_bounds__(256)
scan3_kernel(int* __restrict__ off, const int* __restrict__ part) {
    int p = part[blockIdx.x];
    int base = blockIdx.x * 1024 + threadIdx.x * 4;
#pragma unroll
    for (int i = 0; i < 4; ++i)
        if (base + i < NR) off[base + i] += p;
}

// BIG path: atomic-free scatter using rank. off[] stays EXCLUSIVE STARTS.
__global__ void __launch_bounds__(256)
bucket_fast_kernel(const int* __restrict__ ei, const int* __restrict__ et,
                   const int* __restrict__ off, const int* __restrict__ rank,
                   uint_t* __restrict__ bucket) {
    int e = blockIdx.x * 256 + threadIdx.x;
    if (e < E_EDGES) {
        int src = ei[e];
        int dst = ei[E_EDGES + e];
        int r = et[e];
        int key = r * N_NODES + dst;
        bucket[off[key] + rank[e]] =
            (uint_t)src | ((uint_t)(dst & 63) << 17) | ((uint_t)r << 23);
    }
}

// FALLBACK path: atomic scatter, turns off[] into segment ENDS (fused_kernel
// expects ends semantics).
__global__ void __launch_bounds__(256)
bucket_atomic_kernel(const int* __restrict__ ei, const int* __restrict__ et,
                     int* __restrict__ off, uint_t* __restrict__ bucket) {
    int e = blockIdx.x * 256 + threadIdx.x;
    if (e < E_EDGES) {
        int src = ei[e];
        int dst = ei[E_EDGES + e];
        int r = et[e];
        int key = r * N_NODES + dst;
        int pos = atomicAdd(&off[key], 1);
        bucket[pos] = (uint_t)src | ((uint_t)(dst & 63) << 17) | ((uint_t)r << 23);
    }
}

// One-time: W[r][k][col] fp32 -> Wt[r][col][k] bf16 hi/lo. 36 blocks = (r, k0/32).
__global__ void __launch_bounds__(256)
wt_kernel(const float* __restrict__ W, const float* __restrict__ Wroot,
          ushort_t* __restrict__ WtH, ushort_t* __restrict__ WtL) {
    int r = blockIdx.x >> 2;
    int k0 = (blockIdx.x & 3) * 32;
    const float* Wr = (r < 8) ? (W + ((size_t)r << 14)) : Wroot;
    __shared__ float T[32][129];
    int tid = threadIdx.x;
#pragma unroll
    for (int u = 0; u < 16; ++u) {
        int idx = tid + u * 256;
        T[idx >> 7][idx & 127] = Wr[(size_t)k0 * D + idx];
    }
    __syncthreads();
    int col = tid & 127, kh = tid >> 7;
    ushort8 h0, h1, l0, l1;
#pragma unroll
    for (int kk = 0; kk < 8; ++kk) {
        float f = T[kh * 16 + kk][col];
        ushort_t hb = f2bf(f);
        h0[kk] = hb; l0[kk] = f2bf(f - bf2f(hb));
    }
#pragma unroll
    for (int kk = 0; kk < 8; ++kk) {
        float f = T[kh * 16 + 8 + kk][col];
        ushort_t hb = f2bf(f);
        h1[kk] = hb; l1[kk] = f2bf(f - bf2f(hb));
    }
    size_t o = ((size_t)r << 14) + (size_t)col * D + k0 + kh * 16;
    *(ushort8*)&WtH[o] = h0; *(ushort8*)&WtH[o + 8] = h1;
    *(ushort8*)&WtL[o] = l0; *(ushort8*)&WtL[o + 8] = l1;
}

// BIG kernel 1: one 16-lane group per key; lane-parallel bucket prefetch +
// shfl broadcast kills the dependent-load chain; x rows read in batches of 4.
__global__ void __launch_bounds__(256)
mean_kernel(const float* __restrict__ x, const int* __restrict__ off,
            const uint_t* __restrict__ bucket, ushort_t* __restrict__ Mh) {
    int tid = threadIdx.x;
    int lane = tid & 63;
    int g = blockIdx.x * 16 + (tid >> 4);  // grid covers NR exactly
    int l = tid & 15;
    int gwb = lane & 48;                   // group base lane within wave
    int e0 = off[g];
    int e1 = (g == NR - 1) ? E_EDGES : off[g + 1];
    int cnt = e1 - e0;
    uint_t bw = 0;
    if (l < cnt) bw = bucket[e0 + l];      // lane-parallel prefetch (<=16)

    float a[8] = {0.f, 0.f, 0.f, 0.f, 0.f, 0.f, 0.f, 0.f};
    int npf = cnt < 16 ? cnt : 16;
    for (int p0 = 0; p0 < npf; p0 += 4) {
        int act = npf - p0;
        float4 v0[4], v1[4];
#pragma unroll
        for (int u = 0; u < 4; ++u) {
            int src = __shfl(bw, gwb + p0 + u, 64) & 0x1FFFF;
            const float4* xp = (const float4*)(x + (size_t)src * D + l * 8);
            if (u < act) { v0[u] = xp[0]; v1[u] = xp[1]; }
        }
#pragma unroll
        for (int u = 0; u < 4; ++u) {
            if (u < act) {
                a[0] += v0[u].x; a[1] += v0[u].y; a[2] += v0[u].z; a[3] += v0[u].w;
                a[4] += v1[u].x; a[5] += v1[u].y; a[6] += v1[u].z; a[7] += v1[u].w;
            }
        }
    }
    for (int p = e0 + 16; p < e1; ++p) {   // astronomically rare tail
        int src = bucket[p] & 0x1FFFF;
        const float4* xp = (const float4*)(x + (size_t)src * D + l * 8);
        float4 v0 = xp[0], v1 = xp[1];
        a[0] += v0.x; a[1] += v0.y; a[2] += v0.z; a[3] += v0.w;
        a[4] += v1.x; a[5] += v1.y; a[6] += v1.z; a[7] += v1.w;
    }
    float inv = (cnt > 0) ? 1.0f / (float)cnt : 0.0f;
    ushort8 h;
#pragma unroll
    for (int j = 0; j < 8; ++j) h[j] = f2bf(a[j] * inv);
    *(ushort8*)(Mh + (size_t)g * D + l * 8) = h;
}

// BIG kernel 2: dense GEMM, 2-phase pipelined. Block = 128 dsts, 512 threads.
// 18 stages = 9 rels x 2 K-halves; stage s+1's B (32KB, Bh|Bl) is issued via
// global_load_lds into buf^1 BEFORE computing stage s from buf, so the
// compiler's vmcnt(0)-before-barrier lands after the MFMAs (latency hidden).
// Source-side XOR swizzle (bits 4-6 ^= col bits 1-3 at 128B col stride) undone
// on the ds_read side -> conflict-free (2-way).
__global__ void __launch_bounds__(512, 4)
gemm_kernel(const float* __restrict__ x, const ushort_t* __restrict__ Mh,
            const ushort_t* __restrict__ WtH, const ushort_t* __restrict__ WtL,
            const float* __restrict__ bias, float* __restrict__ out) {
    __shared__ __align__(16) char Bc[65536];  // 2 bufs x (16KB Bh + 16KB Bl)
    int tid = threadIdx.x;
    int lane = tid & 63;
    int wave = tid >> 6;            // 0..7
    int mrow = lane & 15;
    int kg = lane >> 4;
    int n0 = blockIdx.x * 128;
    int row = n0 + wave * 16 + mrow;
    int rowc = row < N_NODES ? row : N_NODES - 1;  // OOB masked in epilogue

    f32x4 acc[8];
#pragma unroll
    for (int t = 0; t < 8; ++t) acc[t] = (f32x4){0.f, 0.f, 0.f, 0.f};

    // stage s (rel = s>>1, kh = s&1) into buffer bufIdx
    auto stage = [&](int s, int bufIdx) {
        int rel = s >> 1, kh = s & 1;
        const char* pH = (const char*)(WtH + ((size_t)rel << 14));
        const char* pL = (const char*)(WtL + ((size_t)rel << 14));
        char* lb = Bc + bufIdx * 32768;
#pragma unroll
        for (int j = 0; j < 4; ++j) {
            int o = j * 8192 + wave * 1024 + lane * 16;  // linear within 32KB
            int oin = o & 16383;                         // within 16KB plane
            int osw = oin ^ ((oin >> 4) & 0x70);         // involution bits 4-6
            int gbyte = (osw >> 7) * 256 + kh * 128 + (osw & 127);
            const char* src = (o < 16384) ? (pH + gbyte) : (pL + gbyte);
            gload_lds16(src, lb + j * 8192 + wave * 1024);
        }
    };
    // A-fragments for stage s (2 ksteps)
    auto loadA = [&](int s, short8* a) {
        int rel = s >> 1, kh = s & 1;
        if (rel < 8) {
            const ushort_t* Ar = Mh + ((size_t)rel * N_NODES + rowc) * D;
            a[0] = *(const short8*)(Ar + (kh * 2 + 0) * 32 + kg * 8);
            a[1] = *(const short8*)(Ar + (kh * 2 + 1) * 32 + kg * 8);
        } else {
            const float* Ax = x + (size_t)rowc * D;
#pragma unroll
            for (int kl = 0; kl < 2; ++kl) {
                int kofs = (kh * 2 + kl) * 32 + kg * 8;
                float4 f0 = *(const float4*)(Ax + kofs);
                float4 f1 = *(const float4*)(Ax + kofs + 4);
                float fv[8] = {f0.x, f0.y, f0.z, f0.w, f1.x, f1.y, f1.z, f1.w};
#pragma unroll
                for (int j = 0; j < 8; ++j) a[kl][j] = (short)f2bf(fv[j]);
            }
        }
    };

    short8 aC[2], aN[2];
    stage(0, 0);
    loadA(0, aC);
    __syncthreads();  // drain stage 0

    for (int s = 0; s < 18; ++s) {
        int cur = s & 1;
        if (s < 17) { stage(s + 1, cur ^ 1); loadA(s + 1, aN); }
        const char* bb = Bc + cur * 32768;
#pragma unroll
        for (int kl = 0; kl < 2; ++kl) {
#pragma unroll
            for (int nt = 0; nt < 8; ++nt) {
                int col = nt * 16 + mrow;
                int rb = col * 128 + kl * 64 + kg * 16;
                int rs = rb ^ ((rb >> 4) & 0x70);
                short8 bh = *(const short8*)(bb + rs);
                short8 bl = *(const short8*)(bb + 16384 + rs);
                acc[nt] = __builtin_amdgcn_mfma_f32_16x16x32_bf16(aC[kl], bh, acc[nt], 0, 0, 0);
                acc[nt] = __builtin_amdgcn_mfma_f32_16x16x32_bf16(aC[kl], bl, acc[nt], 0, 0, 0);
            }
        }
        __syncthreads();  // drains stage s+1 loads; guards buffer reuse
        if (s < 17) { aC[0] = aN[0]; aC[1] = aN[1]; }
    }

    // epilogue: D layout col=lane&15, row=(lane>>4)*4+j (verified rounds 5-11)
#pragma unroll
    for (int nt = 0; nt < 8; ++nt) {
        int col = nt * 16 + mrow;
        float bb = bias[col];
#pragma unroll
        for (int j = 0; j < 4; ++j) {
            int nn = n0 + wave * 16 + kg * 4 + j;
            if (nn < N_NODES) {
                float v = acc[nt][j] + bb;
                out[(size_t)nn * D + col] = v > 0.f ? v : 0.f;
            }
        }
    }
}

// FALLBACK (small ws): round-7 fused kernel, unchanged (ends semantics).
__global__ void __launch_bounds__(256, 4)
fused_kernel(const float* __restrict__ x,
             const ushort_t* __restrict__ WtH, const ushort_t* __restrict__ WtL,
             const float* __restrict__ bias, const int* __restrict__ ends,
             const uint_t* __restrict__ bucket, float* __restrict__ out) {
    __shared__ float At[64][132];
    __shared__ float sinv[64];
    __shared__ int sEnd[64];
    __shared__ float bs[128];
    __shared__ int sBase;

    int tid = threadIdx.x;
    int lane = tid & 63;
    int wave = tid >> 6;
    int mrow = lane & 15;
    int kg = lane >> 4;
    int n0 = blockIdx.x * 64;
    if (tid < 128) bs[tid] = bias[tid];

    f32x4 acc[8];
#pragma unroll
    for (int t = 0; t < 8; ++t) acc[t] = (f32x4){0.f, 0.f, 0.f, 0.f};

    for (int r = 0; r < R; ++r) {
        __syncthreads();
#pragma unroll
        for (int u = 0; u < 33; ++u) ((float*)At)[tid + u * 256] = 0.f;
        if (tid < 64) {
            int n = n0 + tid;
            if (n > N_NODES - 1) n = N_NODES - 1;
            int key = r * N_NODES + n;
            int e1 = ends[key];
            int e0 = (key == 0) ? 0 : ends[key - 1];
            int c = e1 - e0;
            sinv[tid] = (c > 0) ? 1.0f / (float)c : 0.0f;
            sEnd[tid] = e1;
            if (tid == 0) sBase = e0;
        }
        __syncthreads();
        int base = sBase;
        int nItems = (sEnd[63] - base) << 5;

        for (int i = tid; i < nItems; i += 256) {
            uint_t v = bucket[base + (i >> 5)];
            int src = v & 0x1FFFF;
            int dl = (v >> 17) & 63;
            int ch = i & 31;
            float4 xv = *(const float4*)(x + (size_t)src * D + ch * 4);
            float* rp = &At[dl][ch * 4];
            atomicAdd(rp + 0, xv.x);
            atomicAdd(rp + 1, xv.y);
            atomicAdd(rp + 2, xv.z);
            atomicAdd(rp + 3, xv.w);
        }
        __syncthreads();

        const ushort_t* WH = WtH + ((size_t)r << 14);
        const ushort_t* WL = WtL + ((size_t)r << 14);
        int rw = wave * 16 + mrow;
        float iv = sinv[rw];
#pragma unroll
        for (int kstep = 0; kstep < 4; ++kstep) {
            int kofs = kstep * 32 + kg * 8;
            float4 f0 = *(const float4*)&At[rw][kofs];
            float4 f1 = *(const float4*)&At[rw][kofs + 4];
            float fv[8] = {f0.x, f0.y, f0.z, f0.w, f1.x, f1.y, f1.z, f1.w};
            short8 ah, al;
#pragma unroll
            for (int j = 0; j < 8; ++j) {
                float f = fv[j] * iv;
                ushort_t hb = f2bf(f);
                ah[j] = (short)hb;
                al[j] = (short)f2bf(f - bf2f(hb));
            }
#pragma unroll
            for (int nt = 0; nt < 8; ++nt) {
                int col = nt * 16 + mrow;
                short8 bh = *(const short8*)&WH[(size_t)col * D + kofs];
                short8 bl = *(const short8*)&WL[(size_t)col * D + kofs];
                acc[nt] = __builtin_amdgcn_mfma_f32_16x16x32_bf16(ah, bh, acc[nt], 0, 0, 0);
                acc[nt] = __builtin_amdgcn_mfma_f32_16x16x32_bf16(ah, bl, acc[nt], 0, 0, 0);
                acc[nt] = __builtin_amdgcn_mfma_f32_16x16x32_bf16(al, bh, acc[nt], 0, 0, 0);
            }
        }
    }

    {
        const ushort_t* WH = WtH + ((size_t)8 << 14);
        const ushort_t* WL = WtL + ((size_t)8 << 14);
        int n = n0 + wave * 16 + mrow;
#pragma unroll
        for (int kstep = 0; kstep < 4; ++kstep) {
            int kofs = kstep * 32 + kg * 8;
            float fv[8] = {0.f, 0.f, 0.f, 0.f, 0.f, 0.f, 0.f, 0.f};
            if (n < N_NODES) {
                const float4* xp = (const float4*)(x + (size_t)n * D + kofs);
                float4 f0 = xp[0], f1 = xp[1];
                fv[0] = f0.x; fv[1] = f0.y; fv[2] = f0.z; fv[3] = f0.w;
                fv[4] = f1.x; fv[5] = f1.y; fv[6] = f1.z; fv[7] = f1.w;
            }
            short8 ah, al;
#pragma unroll
            for (int j = 0; j < 8; ++j) {
                float f = fv[j];
                ushort_t hb = f2bf(f);
                ah[j] = (short)hb;
                al[j] = (short)f2bf(f - bf2f(hb));
            }
#pragma unroll
            for (int nt = 0; nt < 8; ++nt) {
                int col = nt * 16 + mrow;
                short8 bh = *(const short8*)&WH[(size_t)col * D + kofs];
                short8 bl = *(const short8*)&WL[(size_t)col * D + kofs];
                acc[nt] = __builtin_amdgcn_mfma_f32_16x16x32_bf16(ah, bh, acc[nt], 0, 0, 0);
                acc[nt] = __builtin_amdgcn_mfma_f32_16x16x32_bf16(ah, bl, acc[nt], 0, 0, 0);
                acc[nt] = __builtin_amdgcn_mfma_f32_16x16x32_bf16(al, bh, acc[nt], 0, 0, 0);
            }
        }
    }

#pragma unroll
    for (int nt = 0; nt < 8; ++nt) {
        int col = nt * 16 + mrow;
        float bb = bs[col];
#pragma unroll
        for (int j = 0; j < 4; ++j) {
            int nn = n0 + wave * 16 + kg * 4 + j;
            if (nn < N_NODES) {
                float v = acc[nt][j] + bb;
                out[(size_t)nn * D + col] = v > 0.f ? v : 0.f;
            }
        }
    }
}

extern "C" void kernel_launch(void* const* d_in, const int* in_sizes, int n_in,
                              void* d_out, int out_size, void* d_ws, size_t ws_size,
                              hipStream_t stream) {
    const float* x     = (const float*)d_in[0];
    const int*   ei    = (const int*)d_in[1];
    const int*   et    = (const int*)d_in[2];
    const float* W     = (const float*)d_in[3];
    const float* Wroot = (const float*)d_in[4];
    const float* b     = (const float*)d_in[5];
    float* out = (float*)d_out;
    int* ws = (int*)d_ws;
    int* off = ws;                                        // NR ints
    uint_t* bucket = (uint_t*)(ws + NR);                  // E packed words
    int* rank = ws + NR + E_EDGES;                        // E ints
    ushort_t* WtH = (ushort_t*)(ws + NR + 2 * E_EDGES);   // 9*16384 ushorts
    ushort_t* WtL = WtH + 9 * 16384;
    ushort_t* Mh = (ushort_t*)((char*)d_ws + FIXED_WS_BYTES);  // NR*D bf16-hi

    hipMemsetAsync(d_ws, 0, (size_t)NR * sizeof(int), stream);

    count_kernel<<<(E_EDGES + 255) / 256, 256, 0, stream>>>(ei, et, off, rank);
    wt_kernel<<<36, 256, 0, stream>>>(W, Wroot, WtH, WtL);
    scan1_kernel<<<SCAN_BLOCKS, 256, 0, stream>>>(off, (int*)bucket);
    scan2_kernel<<<1, 512, 0, stream>>>((int*)bucket);
    scan3_kernel<<<SCAN_BLOCKS, 256, 0, stream>>>(off, (int*)bucket);

    if (ws_size >= BIG_WS_BYTES) {
        bucket_fast_kernel<<<(E_EDGES + 255) / 256, 256, 0, stream>>>(ei, et, off,
                                                                      rank, bucket);
        mean_kernel<<<NR / 16, 256, 0, stream>>>(x, off, bucket, Mh);
        gemm_kernel<<<(N_NODES + 127) / 128, 512, 0, stream>>>(x, Mh, WtH, WtL, b, out);
    } else {
        bucket_atomic_kernel<<<(E_EDGES + 255) / 256, 256, 0, stream>>>(ei, et, off,
                                                                        bucket);
        fused_kernel<<<(N_NODES + 63) / 64, 256, 0, stream>>>(x, WtH, WtL, b, off,
                                                              bucket, out);
    }
}

// Round 13
// 138.252 us; speedup vs baseline: 5.1325x; 1.1003x over previous
//
#include <hip/hip_runtime.h>

#define N_NODES 50000
#define D 128
#define R 8
#define E_EDGES 600000
#define NR (N_NODES * R)                 // 400000 (rel,dst) keys: key = r*N + dst
#define SCAN_BLOCKS ((NR + 1023) / 1024) // 391 (fallback path only)
#define SLOTS_K 16

typedef unsigned short ushort_t;
typedef unsigned int uint_t;
typedef __attribute__((ext_vector_type(8))) short short8;
typedef __attribute__((ext_vector_type(8))) ushort_t ushort8;
typedef __attribute__((ext_vector_type(4))) float f32x4;

// ws layout (big path):
//   cnt    NR ints            per-key edge counts (memset 0)
//   slots  NR*16 ints         first <=16 src ids per key (no init needed)
//   WtH    9*16384 ushorts    W^T bf16 hi    WtL same (lo)
//   Mh     NR*D ushorts       bf16-hi means (102.4 MB)
// total ~130.2 MB (harness provides >=209 MB per rounds 8-12 evidence)
#define FIXED_WS_BYTES ((size_t)NR * (1 + SLOTS_K) * 4 + (size_t)2 * 9 * 16384 * 2)
#define BIG_WS_BYTES (FIXED_WS_BYTES + (size_t)NR * D * 2)

static __device__ __forceinline__ ushort_t f2bf(float f) {
    uint_t u = __float_as_uint(f);
    uint_t r = u + 0x7fffu + ((u >> 16) & 1u);
    return (ushort_t)(r >> 16);
}
static __device__ __forceinline__ float bf2f(ushort_t h) {
    return __uint_as_float(((uint_t)h) << 16);
}

// Direct global->LDS DMA, 16B per lane. LDS dest = wave-uniform base + lane*16.
static __device__ __forceinline__ void gload_lds16(const void* g, void* l) {
    __builtin_amdgcn_global_load_lds(
        (const __attribute__((address_space(1))) unsigned int*)g,
        (__attribute__((address_space(3))) unsigned int*)l, 16, 0, 0);
}

// BIG path: count + first-16 slot table (replaces scan+bucket+rank entirely)
__global__ void __launch_bounds__(256)
count_slots_kernel(const int* __restrict__ ei, const int* __restrict__ et,
                   int* __restrict__ cnt, int* __restrict__ slots) {
    int e = blockIdx.x * 256 + threadIdx.x;
    if (e < E_EDGES) {
        int src = ei[e];
        int dst = ei[E_EDGES + e];
        int r = et[e];
        int key = r * N_NODES + dst;
        int pos = atomicAdd(&cnt[key], 1);
        if (pos < SLOTS_K) slots[(size_t)key * SLOTS_K + pos] = src;
    }
}

// One-time: W[r][k][col] fp32 -> Wt[r][col][k] bf16 hi/lo. 36 blocks = (r, k0/32).
__global__ void __launch_bounds__(256)
wt_kernel(const float* __restrict__ W, const float* __restrict__ Wroot,
          ushort_t* __restrict__ WtH, ushort_t* __restrict__ WtL) {
    int r = blockIdx.x >> 2;
    int k0 = (blockIdx.x & 3) * 32;
    const float* Wr = (r < 8) ? (W + ((size_t)r << 14)) : Wroot;
    __shared__ float T[32][129];
    int tid = threadIdx.x;
#pragma unroll
    for (int u = 0; u < 16; ++u) {
        int idx = tid + u * 256;
        T[idx >> 7][idx & 127] = Wr[(size_t)k0 * D + idx];
    }
    __syncthreads();
    int col = tid & 127, kh = tid >> 7;
    ushort8 h0, h1, l0, l1;
#pragma unroll
    for (int kk = 0; kk < 8; ++kk) {
        float f = T[kh * 16 + kk][col];
        ushort_t hb = f2bf(f);
        h0[kk] = hb; l0[kk] = f2bf(f - bf2f(hb));
    }
#pragma unroll
    for (int kk = 0; kk < 8; ++kk) {
        float f = T[kh * 16 + 8 + kk][col];
        ushort_t hb = f2bf(f);
        h1[kk] = hb; l1[kk] = f2bf(f - bf2f(hb));
    }
    size_t o = ((size_t)r << 14) + (size_t)col * D + k0 + kh * 16;
    *(ushort8*)&WtH[o] = h0; *(ushort8*)&WtH[o + 8] = h1;
    *(ushort8*)&WtL[o] = l0; *(ushort8*)&WtL[o + 8] = l1;
}

// BIG kernel 1: one 16-lane group per key. cnt==0 -> skip entirely (gemm
// masks those rows). cnt<=16 -> slots fast path (lane-parallel prefetch +
// shfl broadcast, x rows in batches of 4). cnt>16 (P ~1e-5 for this data) ->
// deterministic full edge-list rescan (slot subset is atomic-order-dependent).
__global__ void __launch_bounds__(256)
mean_kernel(const float* __restrict__ x, const int* __restrict__ ei,
            const int* __restrict__ et, const int* __restrict__ cnt,
            const int* __restrict__ slots, ushort_t* __restrict__ Mh) {
    int tid = threadIdx.x;
    int lane = tid & 63;
    int g = blockIdx.x * 16 + (tid >> 4);  // grid covers NR exactly
    int l = tid & 15;
    int gwb = lane & 48;                   // group base lane within wave
    int c = cnt[g];
    if (c == 0) return;

    float a[8] = {0.f, 0.f, 0.f, 0.f, 0.f, 0.f, 0.f, 0.f};
    if (c <= SLOTS_K) {
        int bw = 0;
        if (l < c) bw = slots[(size_t)g * SLOTS_K + l];  // lane-parallel prefetch
        for (int p0 = 0; p0 < c; p0 += 4) {
            int act = c - p0;
            float4 v0[4], v1[4];
#pragma unroll
            for (int u = 0; u < 4; ++u) {
                int src = __shfl(bw, gwb + p0 + u, 64);
                const float4* xp = (const float4*)(x + (size_t)src * D + l * 8);
                if (u < act) { v0[u] = xp[0]; v1[u] = xp[1]; }
            }
#pragma unroll
            for (int u = 0; u < 4; ++u) {
                if (u < act) {
                    a[0] += v0[u].x; a[1] += v0[u].y; a[2] += v0[u].z; a[3] += v0[u].w;
                    a[4] += v1[u].x; a[5] += v1[u].y; a[6] += v1[u].z; a[7] += v1[u].w;
                }
            }
        }
    } else {
        // slow path: recompute the full sum from the edge list (deterministic)
        int rel = g / N_NODES;
        int dn = g - rel * N_NODES;
        for (int e = 0; e < E_EDGES; ++e) {
            if (et[e] == rel && ei[E_EDGES + e] == dn) {
                int src = ei[e];
                const float4* xp = (const float4*)(x + (size_t)src * D + l * 8);
                float4 v0 = xp[0], v1 = xp[1];
                a[0] += v0.x; a[1] += v0.y; a[2] += v0.z; a[3] += v0.w;
                a[4] += v1.x; a[5] += v1.y; a[6] += v1.z; a[7] += v1.w;
            }
        }
    }
    float inv = 1.0f / (float)c;
    ushort8 h;
#pragma unroll
    for (int j = 0; j < 8; ++j) h[j] = f2bf(a[j] * inv);
    *(ushort8*)(Mh + (size_t)g * D + l * 8) = h;
}

// BIG kernel 2: dense GEMM, 2-phase pipelined (verified round 12). Block =
// 128 dsts, 512 threads. Per stage: next B half (32KB Bh|Bl) issued via
// global_load_lds before computing current (vmcnt drain lands after MFMAs).
// Source-side XOR swizzle undone on ds_read side. NEW: A-frag masked to zero
// when cnt==0 (exec-masked load -> ~22% of Mh never fetched).
__global__ void __launch_bounds__(512, 4)
gemm_kernel(const float* __restrict__ x, const ushort_t* __restrict__ Mh,
            const ushort_t* __restrict__ WtH, const ushort_t* __restrict__ WtL,
            const int* __restrict__ cnt, const float* __restrict__ bias,
            float* __restrict__ out) {
    __shared__ __align__(16) char Bc[65536];  // 2 bufs x (16KB Bh + 16KB Bl)
    int tid = threadIdx.x;
    int lane = tid & 63;
    int wave = tid >> 6;            // 0..7
    int mrow = lane & 15;
    int kg = lane >> 4;
    int n0 = blockIdx.x * 128;
    int row = n0 + wave * 16 + mrow;
    int rowc = row < N_NODES ? row : N_NODES - 1;  // OOB masked in epilogue

    f32x4 acc[8];
#pragma unroll
    for (int t = 0; t < 8; ++t) acc[t] = (f32x4){0.f, 0.f, 0.f, 0.f};

    auto stage = [&](int s, int bufIdx) {
        int rel = s >> 1, kh = s & 1;
        const char* pH = (const char*)(WtH + ((size_t)rel << 14));
        const char* pL = (const char*)(WtL + ((size_t)rel << 14));
        char* lb = Bc + bufIdx * 32768;
#pragma unroll
        for (int j = 0; j < 4; ++j) {
            int o = j * 8192 + wave * 1024 + lane * 16;  // linear within 32KB
            int oin = o & 16383;                         // within 16KB plane
            int osw = oin ^ ((oin >> 4) & 0x70);         // involution bits 4-6
            int gbyte = (osw >> 7) * 256 + kh * 128 + (osw & 127);
            const char* src = (o < 16384) ? (pH + gbyte) : (pL + gbyte);
            gload_lds16(src, lb + j * 8192 + wave * 1024);
        }
    };
    auto loadA = [&](int s, short8* a) {
        int rel = s >> 1, kh = s & 1;
        if (rel < 8) {
            int cv = cnt[rel * N_NODES + rowc];
            if (cv > 0) {
                const ushort_t* Ar = Mh + ((size_t)rel * N_NODES + rowc) * D;
                a[0] = *(const short8*)(Ar + (kh * 2 + 0) * 32 + kg * 8);
                a[1] = *(const short8*)(Ar + (kh * 2 + 1) * 32 + kg * 8);
            } else {
#pragma unroll
                for (int j = 0; j < 8; ++j) { a[0][j] = 0; a[1][j] = 0; }
            }
        } else {
            const float* Ax = x + (size_t)rowc * D;
#pragma unroll
            for (int kl = 0; kl < 2; ++kl) {
                int kofs = (kh * 2 + kl) * 32 + kg * 8;
                float4 f0 = *(const float4*)(Ax + kofs);
                float4 f1 = *(const float4*)(Ax + kofs + 4);
                float fv[8] = {f0.x, f0.y, f0.z, f0.w, f1.x, f1.y, f1.z, f1.w};
#pragma unroll
                for (int j = 0; j < 8; ++j) a[kl][j] = (short)f2bf(fv[j]);
            }
        }
    };

    short8 aC[2], aN[2];
    stage(0, 0);
    loadA(0, aC);
    __syncthreads();  // drain stage 0

    for (int s = 0; s < 18; ++s) {
        int cur = s & 1;
        if (s < 17) { stage(s + 1, cur ^ 1); loadA(s + 1, aN); }
        const char* bb = Bc + cur * 32768;
#pragma unroll
        for (int kl = 0; kl < 2; ++kl) {
#pragma unroll
            for (int nt = 0; nt < 8; ++nt) {
                int col = nt * 16 + mrow;
                int rb = col * 128 + kl * 64 + kg * 16;
                int rs = rb ^ ((rb >> 4) & 0x70);
                short8 bh = *(const short8*)(bb + rs);
                short8 bl = *(const short8*)(bb + 16384 + rs);
                acc[nt] = __builtin_amdgcn_mfma_f32_16x16x32_bf16(aC[kl], bh, acc[nt], 0, 0, 0);
                acc[nt] = __builtin_amdgcn_mfma_f32_16x16x32_bf16(aC[kl], bl, acc[nt], 0, 0, 0);
            }
        }
        __syncthreads();  // drains stage s+1 loads; guards buffer reuse
        if (s < 17) { aC[0] = aN[0]; aC[1] = aN[1]; }
    }

    // epilogue: D layout col=lane&15, row=(lane>>4)*4+j (verified rounds 5-12)
#pragma unroll
    for (int nt = 0; nt < 8; ++nt) {
        int col = nt * 16 + mrow;
        float bb = bias[col];
#pragma unroll
        for (int j = 0; j < 4; ++j) {
            int nn = n0 + wave * 16 + kg * 4 + j;
            if (nn < N_NODES) {
                float v = acc[nt][j] + bb;
                out[(size_t)nn * D + col] = v > 0.f ? v : 0.f;
            }
        }
    }
}

// ---------------- FALLBACK path (small ws; never taken per R8-12 evidence) --
__global__ void __launch_bounds__(256)
count_fb_kernel(const int* __restrict__ ei, const int* __restrict__ et,
                int* __restrict__ cnt) {
    int e = blockIdx.x * 256 + threadIdx.x;
    if (e < E_EDGES) {
        int dst = ei[E_EDGES + e];
        int r = et[e];
        atomicAdd(&cnt[r * N_NODES + dst], 1);
    }
}

__global__ void __launch_bounds__(256)
scan1_kernel(int* __restrict__ off, int* __restrict__ part) {
    __shared__ int wsum[4];
    int tid = threadIdx.x, lane = tid & 63, wid = tid >> 6;
    int base = blockIdx.x * 1024 + tid * 4;
    int c0 = 0, c1 = 0, c2 = 0, c3 = 0;
    if (base + 0 < NR) c0 = off[base + 0];
    if (base + 1 < NR) c1 = off[base + 1];
    if (base + 2 < NR) c2 = off[base + 2];
    if (base + 3 < NR) c3 = off[base + 3];
    int ts = c0 + c1 + c2 + c3;
    int v = ts;
#pragma unroll
    for (int o = 1; o < 64; o <<= 1) {
        int u = __shfl_up(v, o, 64);
        if (lane >= o) v += u;
    }
    if (lane == 63) wsum[wid] = v;
    __syncthreads();
    int wbase = 0;
#pragma unroll
    for (int w = 0; w < 4; ++w)
        if (w < wid) wbase += wsum[w];
    int excl = wbase + v - ts;
    if (base + 0 < NR) off[base + 0] = excl;
    if (base + 1 < NR) off[base + 1] = excl + c0;
    if (base + 2 < NR) off[base + 2] = excl + c0 + c1;
    if (base + 3 < NR) off[base + 3] = excl + c0 + c1 + c2;
    if (tid == 0) part[blockIdx.x] = wsum[0] + wsum[1] + wsum[2] + wsum[3];
}

__global__ void __launch_bounds__(512)
scan2_kernel(int* __restrict__ part) {
    __shared__ int ws8[8];
    int t = threadIdx.x, lane = t & 63, w = t >> 6;
    int v = (t < SCAN_BLOCKS) ? part[t] : 0;
    int s = v;
#pragma unroll
    for (int o = 1; o < 64; o <<= 1) {
        int u = __shfl_up(s, o, 64);
        if (lane >= o) s += u;
    }
    if (lane == 63) ws8[w] = s;
    __syncthreads();
    int wb = 0;
#pragma unroll
    for (int i = 0; i < 8; ++i)
        if (i < w) wb += ws8[i];
    if (t < SCAN_BLOCKS) part[t] = wb + s - v;
}

__global__ void __launch_bounds__(256)
scan3_kernel(int* __restrict__ off, const int* __restrict__ part) {
    int p = part[blockIdx.x];
    int base = blockIdx.x * 1024 + threadIdx.x * 4;
#pragma unroll
    for (int i = 0; i < 4; ++i)
        if (base + i < NR) off[base + i] += p;
}

__global__ void __launch_bounds__(256)
bucket_atomic_kernel(const int* __restrict__ ei, const int* __restrict__ et,
                     int* __restrict__ off, uint_t* __restrict__ bucket) {
    int e = blockIdx.x * 256 + threadIdx.x;
    if (e < E_EDGES) {
        int src = ei[e];
        int dst = ei[E_EDGES + e];
        int r = et[e];
        int key = r * N_NODES + dst;
        int pos = atomicAdd(&off[key], 1);
        bucket[pos] = (uint_t)src | ((uint_t)(dst & 63) << 17) | ((uint_t)r << 23);
    }
}

__global__ void __launch_bounds__(256, 4)
fused_kernel(const float* __restrict__ x,
             const ushort_t* __restrict__ WtH, const ushort_t* __restrict__ WtL,
             const float* __restrict__ bias, const int* __restrict__ ends,
             const uint_t* __restrict__ bucket, float* __restrict__ out) {
    __shared__ float At[64][132];
    __shared__ float sinv[64];
    __shared__ int sEnd[64];
    __shared__ float bs[128];
    __shared__ int sBase;

    int tid = threadIdx.x;
    int lane = tid & 63;
    int wave = tid >> 6;
    int mrow = lane & 15;
    int kg = lane >> 4;
    int n0 = blockIdx.x * 64;
    if (tid < 128) bs[tid] = bias[tid];

    f32x4 acc[8];
#pragma unroll
    for (int t = 0; t < 8; ++t) acc[t] = (f32x4){0.f, 0.f, 0.f, 0.f};

    for (int r = 0; r < R; ++r) {
        __syncthreads();
#pragma unroll
        for (int u = 0; u < 33; ++u) ((float*)At)[tid + u * 256] = 0.f;
        if (tid < 64) {
            int n = n0 + tid;
            if (n > N_NODES - 1) n = N_NODES - 1;
            int key = r * N_NODES + n;
            int e1 = ends[key];
            int e0 = (key == 0) ? 0 : ends[key - 1];
            int c = e1 - e0;
            sinv[tid] = (c > 0) ? 1.0f / (float)c : 0.0f;
            sEnd[tid] = e1;
            if (tid == 0) sBase = e0;
        }
        __syncthreads();
        int base = sBase;
        int nItems = (sEnd[63] - base) << 5;

        for (int i = tid; i < nItems; i += 256) {
            uint_t v = bucket[base + (i >> 5)];
            int src = v & 0x1FFFF;
            int dl = (v >> 17) & 63;
            int ch = i & 31;
            float4 xv = *(const float4*)(x + (size_t)src * D + ch * 4);
            float* rp = &At[dl][ch * 4];
            atomicAdd(rp + 0, xv.x);
            atomicAdd(rp + 1, xv.y);
            atomicAdd(rp + 2, xv.z);
            atomicAdd(rp + 3, xv.w);
        }
        __syncthreads();

        const ushort_t* WH = WtH + ((size_t)r << 14);
        const ushort_t* WL = WtL + ((size_t)r << 14);
        int rw = wave * 16 + mrow;
        float iv = sinv[rw];
#pragma unroll
        for (int kstep = 0; kstep < 4; ++kstep) {
            int kofs = kstep * 32 + kg * 8;
            float4 f0 = *(const float4*)&At[rw][kofs];
            float4 f1 = *(const float4*)&At[rw][kofs + 4];
            float fv[8] = {f0.x, f0.y, f0.z, f0.w, f1.x, f1.y, f1.z, f1.w};
            short8 ah, al;
#pragma unroll
            for (int j = 0; j < 8; ++j) {
                float f = fv[j] * iv;
                ushort_t hb = f2bf(f);
                ah[j] = (short)hb;
                al[j] = (short)f2bf(f - bf2f(hb));
            }
#pragma unroll
            for (int nt = 0; nt < 8; ++nt) {
                int col = nt * 16 + mrow;
                short8 bh = *(const short8*)&WH[(size_t)col * D + kofs];
                short8 bl = *(const short8*)&WL[(size_t)col * D + kofs];
                acc[nt] = __builtin_amdgcn_mfma_f32_16x16x32_bf16(ah, bh, acc[nt], 0, 0, 0);
                acc[nt] = __builtin_amdgcn_mfma_f32_16x16x32_bf16(ah, bl, acc[nt], 0, 0, 0);
                acc[nt] = __builtin_amdgcn_mfma_f32_16x16x32_bf16(al, bh, acc[nt], 0, 0, 0);
            }
        }
    }

    {
        const ushort_t* WH = WtH + ((size_t)8 << 14);
        const ushort_t* WL = WtL + ((size_t)8 << 14);
        int n = n0 + wave * 16 + mrow;
#pragma unroll
        for (int kstep = 0; kstep < 4; ++kstep) {
            int kofs = kstep * 32 + kg * 8;
            float fv[8] = {0.f, 0.f, 0.f, 0.f, 0.f, 0.f, 0.f, 0.f};
            if (n < N_NODES) {
                const float4* xp = (const float4*)(x + (size_t)n * D + kofs);
                float4 f0 = xp[0], f1 = xp[1];
                fv[0] = f0.x; fv[1] = f0.y; fv[2] = f0.z; fv[3] = f0.w;
                fv[4] = f1.x; fv[5] = f1.y; fv[6] = f1.z; fv[7] = f1.w;
            }
            short8 ah, al;
#pragma unroll
            for (int j = 0; j < 8; ++j) {
                float f = fv[j];
                ushort_t hb = f2bf(f);
                ah[j] = (short)hb;
                al[j] = (short)f2bf(f - bf2f(hb));
            }
#pragma unroll
            for (int nt = 0; nt < 8; ++nt) {
                int col = nt * 16 + mrow;
                short8 bh = *(const short8*)&WH[(size_t)col * D + kofs];
                short8 bl = *(const short8*)&WL[(size_t)col * D + kofs];
                acc[nt] = __builtin_amdgcn_mfma_f32_16x16x32_bf16(ah, bh, acc[nt], 0, 0, 0);
                acc[nt] = __builtin_amdgcn_mfma_f32_16x16x32_bf16(ah, bl, acc[nt], 0, 0, 0);
                acc[nt] = __builtin_amdgcn_mfma_f32_16x16x32_bf16(al, bh, acc[nt], 0, 0, 0);
            }
        }
    }

#pragma unroll
    for (int nt = 0; nt < 8; ++nt) {
        int col = nt * 16 + mrow;
        float bb = bs[col];
#pragma unroll
        for (int j = 0; j < 4; ++j) {
            int nn = n0 + wave * 16 + kg * 4 + j;
            if (nn < N_NODES) {
                float v = acc[nt][j] + bb;
                out[(size_t)nn * D + col] = v > 0.f ? v : 0.f;
            }
        }
    }
}

extern "C" void kernel_launch(void* const* d_in, const int* in_sizes, int n_in,
                              void* d_out, int out_size, void* d_ws, size_t ws_size,
                              hipStream_t stream) {
    const float* x     = (const float*)d_in[0];
    const int*   ei    = (const int*)d_in[1];
    const int*   et    = (const int*)d_in[2];
    const float* W     = (const float*)d_in[3];
    const float* Wroot = (const float*)d_in[4];
    const float* b     = (const float*)d_in[5];
    float* out = (float*)d_out;
    int* ws = (int*)d_ws;

    if (ws_size >= BIG_WS_BYTES) {
        int* cnt = ws;                                        // NR ints
        int* slots = ws + NR;                                 // NR*16 ints
        ushort_t* WtH = (ushort_t*)(ws + NR + NR * SLOTS_K);  // 9*16384 ushorts
        ushort_t* WtL = WtH + 9 * 16384;
        ushort_t* Mh = WtL + 9 * 16384;                       // NR*D bf16-hi

        hipMemsetAsync(cnt, 0, (size_t)NR * sizeof(int), stream);
        count_slots_kernel<<<(E_EDGES + 255) / 256, 256, 0, stream>>>(ei, et, cnt,
                                                                      slots);
        wt_kernel<<<36, 256, 0, stream>>>(W, Wroot, WtH, WtL);
        mean_kernel<<<NR / 16, 256, 0, stream>>>(x, ei, et, cnt, slots, Mh);
        gemm_kernel<<<(N_NODES + 127) / 128, 512, 0, stream>>>(x, Mh, WtH, WtL, cnt,
                                                               b, out);
    } else {
        int* off = ws;                                   // NR ints
        uint_t* bucket = (uint_t*)(ws + NR);             // E packed words
        ushort_t* WtH = (ushort_t*)(ws + NR + E_EDGES);  // 9*16384 ushorts
        ushort_t* WtL = WtH + 9 * 16384;

        hipMemsetAsync(off, 0, (size_t)NR * sizeof(int), stream);
        count_fb_kernel<<<(E_EDGES + 255) / 256, 256, 0, stream>>>(ei, et, off);
        wt_kernel<<<36, 256, 0, stream>>>(W, Wroot, WtH, WtL);
        scan1_kernel<<<SCAN_BLOCKS, 256, 0, stream>>>(off, (int*)bucket);
        scan2_kernel<<<1, 512, 0, stream>>>((int*)bucket);
        scan3_kernel<<<SCAN_BLOCKS, 256, 0, stream>>>(off, (int*)bucket);
        bucket_atomic_kernel<<<(E_EDGES + 255) / 256, 256, 0, stream>>>(ei, et, off,
                                                                        bucket);
        fused_kernel<<<(N_NODES + 63) / 64, 256, 0, stream>>>(x, WtH, WtL, b, off,
                                                              bucket, out);
    }
}

// Round 14
// 126.861 us; speedup vs baseline: 5.5934x; 1.0898x over previous
//
#include <hip/hip_runtime.h>

#define N_NODES 50000
#define D 128
#define R 8
#define E_EDGES 600000
#define NR (N_NODES * R)                 // 400000 (rel,dst) keys: key = r*N + dst
#define SCAN_BLOCKS ((NR + 1023) / 1024) // 391 (fallback path only)
#define SLOTS_K 16

typedef unsigned short ushort_t;
typedef unsigned int uint_t;
typedef __attribute__((ext_vector_type(8))) short short8;
typedef __attribute__((ext_vector_type(8))) ushort_t ushort8;
typedef __attribute__((ext_vector_type(4))) float f32x4;

// ws layout (big path):
//   cnt    NR ints            per-key edge counts (memset 0)
//   slots  NR*16 ints         first <=16 src ids per key (no init needed)
//   WtH    9*16384 ushorts    W^T bf16 hi    WtL same (lo)
//   Mh     NR*D ushorts       bf16-hi means (102.4 MB)
//   xb     N*D ushorts        bf16 x table (12.8 MB)
// total ~143 MB (harness provides >=209 MB per rounds 8-13 evidence)
#define FIXED_WS_BYTES ((size_t)NR * (1 + SLOTS_K) * 4 + (size_t)2 * 9 * 16384 * 2)
#define BIG_WS_BYTES (FIXED_WS_BYTES + (size_t)NR * D * 2 + (size_t)N_NODES * D * 2)

static __device__ __forceinline__ ushort_t f2bf(float f) {
    uint_t u = __float_as_uint(f);
    uint_t r = u + 0x7fffu + ((u >> 16) & 1u);
    return (ushort_t)(r >> 16);
}
static __device__ __forceinline__ float bf2f(ushort_t h) {
    return __uint_as_float(((uint_t)h) << 16);
}

// Direct global->LDS DMA, 16B per lane. LDS dest = wave-uniform base + lane*16.
static __device__ __forceinline__ void gload_lds16(const void* g, void* l) {
    __builtin_amdgcn_global_load_lds(
        (const __attribute__((address_space(1))) unsigned int*)g,
        (__attribute__((address_space(3))) unsigned int*)l, 16, 0, 0);
}

// x fp32 -> bf16 table (one-time; same rounding as gemm's old in-reg f2bf)
__global__ void __launch_bounds__(256)
xb_kernel(const float* __restrict__ x, ushort_t* __restrict__ xb) {
    int i = blockIdx.x * 256 + threadIdx.x;  // grid covers N*D/8 exactly
    const float4* xp = (const float4*)(x + (size_t)i * 8);
    float4 f0 = xp[0], f1 = xp[1];
    ushort8 h;
    h[0] = f2bf(f0.x); h[1] = f2bf(f0.y); h[2] = f2bf(f0.z); h[3] = f2bf(f0.w);
    h[4] = f2bf(f1.x); h[5] = f2bf(f1.y); h[6] = f2bf(f1.z); h[7] = f2bf(f1.w);
    *(ushort8*)(xb + (size_t)i * 8) = h;
}

// BIG path: count + first-16 slot table
__global__ void __launch_bounds__(256)
count_slots_kernel(const int* __restrict__ ei, const int* __restrict__ et,
                   int* __restrict__ cnt, int* __restrict__ slots) {
    int e = blockIdx.x * 256 + threadIdx.x;
    if (e < E_EDGES) {
        int src = ei[e];
        int dst = ei[E_EDGES + e];
        int r = et[e];
        int key = r * N_NODES + dst;
        int pos = atomicAdd(&cnt[key], 1);
        if (pos < SLOTS_K) slots[(size_t)key * SLOTS_K + pos] = src;
    }
}

// One-time: W[r][k][col] fp32 -> Wt[r][col][k] bf16 hi/lo. 36 blocks = (r, k0/32).
__global__ void __launch_bounds__(256)
wt_kernel(const float* __restrict__ W, const float* __restrict__ Wroot,
          ushort_t* __restrict__ WtH, ushort_t* __restrict__ WtL) {
    int r = blockIdx.x >> 2;
    int k0 = (blockIdx.x & 3) * 32;
    const float* Wr = (r < 8) ? (W + ((size_t)r << 14)) : Wroot;
    __shared__ float T[32][129];
    int tid = threadIdx.x;
#pragma unroll
    for (int u = 0; u < 16; ++u) {
        int idx = tid + u * 256;
        T[idx >> 7][idx & 127] = Wr[(size_t)k0 * D + idx];
    }
    __syncthreads();
    int col = tid & 127, kh = tid >> 7;
    ushort8 h0, h1, l0, l1;
#pragma unroll
    for (int kk = 0; kk < 8; ++kk) {
        float f = T[kh * 16 + kk][col];
        ushort_t hb = f2bf(f);
        h0[kk] = hb; l0[kk] = f2bf(f - bf2f(hb));
    }
#pragma unroll
    for (int kk = 0; kk < 8; ++kk) {
        float f = T[kh * 16 + 8 + kk][col];
        ushort_t hb = f2bf(f);
        h1[kk] = hb; l1[kk] = f2bf(f - bf2f(hb));
    }
    size_t o = ((size_t)r << 14) + (size_t)col * D + k0 + kh * 16;
    *(ushort8*)&WtH[o] = h0; *(ushort8*)&WtH[o + 8] = h1;
    *(ushort8*)&WtL[o] = l0; *(ushort8*)&WtL[o + 8] = l1;
}

// BIG kernel 1: one 16-lane group per key; gathers bf16 x rows (256B, half the
// fp32 traffic); fp32 accumulate. cnt==0 skipped (gemm masks). cnt>16
// (P ~1e-5) -> deterministic full edge-list rescan.
__global__ void __launch_bounds__(256)
mean_kernel(const ushort_t* __restrict__ xb, const int* __restrict__ ei,
            const int* __restrict__ et, const int* __restrict__ cnt,
            const int* __restrict__ slots, ushort_t* __restrict__ Mh) {
    int tid = threadIdx.x;
    int lane = tid & 63;
    int g = blockIdx.x * 16 + (tid >> 4);  // grid covers NR exactly
    int l = tid & 15;
    int gwb = lane & 48;                   // group base lane within wave
    int c = cnt[g];
    if (c == 0) return;

    float a[8] = {0.f, 0.f, 0.f, 0.f, 0.f, 0.f, 0.f, 0.f};
    if (c <= SLOTS_K) {
        int bw = 0;
        if (l < c) bw = slots[(size_t)g * SLOTS_K + l];  // lane-parallel prefetch
        for (int p0 = 0; p0 < c; p0 += 4) {
            int act = c - p0;
            ushort8 v[4];
#pragma unroll
            for (int u = 0; u < 4; ++u) {
                int src = __shfl(bw, gwb + p0 + u, 64);
                const ushort8* xp = (const ushort8*)(xb + (size_t)src * D + l * 8);
                if (u < act) v[u] = *xp;
            }
#pragma unroll
            for (int u = 0; u < 4; ++u) {
                if (u < act) {
#pragma unroll
                    for (int j = 0; j < 8; ++j) a[j] += bf2f(v[u][j]);
                }
            }
        }
    } else {
        // slow path: recompute the full sum from the edge list (deterministic)
        int rel = g / N_NODES;
        int dn = g - rel * N_NODES;
        for (int e = 0; e < E_EDGES; ++e) {
            if (et[e] == rel && ei[E_EDGES + e] == dn) {
                int src = ei[e];
                const ushort8* xp = (const ushort8*)(xb + (size_t)src * D + l * 8);
                ushort8 v = *xp;
#pragma unroll
                for (int j = 0; j < 8; ++j) a[j] += bf2f(v[j]);
            }
        }
    }
    float inv = 1.0f / (float)c;
    ushort8 h;
#pragma unroll
    for (int j = 0; j < 8; ++j) h[j] = f2bf(a[j] * inv);
    *(ushort8*)(Mh + (size_t)g * D + l * 8) = h;
}

// BIG kernel 2: dense GEMM, 2-phase pipelined (verified rounds 12-13).
// Root relation A now reads xb directly (bit-identical to old in-reg f2bf).
__global__ void __launch_bounds__(512, 4)
gemm_kernel(const ushort_t* __restrict__ xb, const ushort_t* __restrict__ Mh,
            const ushort_t* __restrict__ WtH, const ushort_t* __restrict__ WtL,
            const int* __restrict__ cnt, const float* __restrict__ bias,
            float* __restrict__ out) {
    __shared__ __align__(16) char Bc[65536];  // 2 bufs x (16KB Bh + 16KB Bl)
    int tid = threadIdx.x;
    int lane = tid & 63;
    int wave = tid >> 6;            // 0..7
    int mrow = lane & 15;
    int kg = lane >> 4;
    int n0 = blockIdx.x * 128;
    int row = n0 + wave * 16 + mrow;
    int rowc = row < N_NODES ? row : N_NODES - 1;  // OOB masked in epilogue

    f32x4 acc[8];
#pragma unroll
    for (int t = 0; t < 8; ++t) acc[t] = (f32x4){0.f, 0.f, 0.f, 0.f};

    auto stage = [&](int s, int bufIdx) {
        int rel = s >> 1, kh = s & 1;
        const char* pH = (const char*)(WtH + ((size_t)rel << 14));
        const char* pL = (const char*)(WtL + ((size_t)rel << 14));
        char* lb = Bc + bufIdx * 32768;
#pragma unroll
        for (int j = 0; j < 4; ++j) {
            int o = j * 8192 + wave * 1024 + lane * 16;  // linear within 32KB
            int oin = o & 16383;                         // within 16KB plane
            int osw = oin ^ ((oin >> 4) & 0x70);         // involution bits 4-6
            int gbyte = (osw >> 7) * 256 + kh * 128 + (osw & 127);
            const char* src = (o < 16384) ? (pH + gbyte) : (pL + gbyte);
            gload_lds16(src, lb + j * 8192 + wave * 1024);
        }
    };
    auto loadA = [&](int s, short8* a) {
        int rel = s >> 1, kh = s & 1;
        if (rel < 8) {
            int cv = cnt[rel * N_NODES + rowc];
            if (cv > 0) {
                const ushort_t* Ar = Mh + ((size_t)rel * N_NODES + rowc) * D;
                a[0] = *(const short8*)(Ar + (kh * 2 + 0) * 32 + kg * 8);
                a[1] = *(const short8*)(Ar + (kh * 2 + 1) * 32 + kg * 8);
            } else {
#pragma unroll
                for (int j = 0; j < 8; ++j) { a[0][j] = 0; a[1][j] = 0; }
            }
        } else {
            const ushort_t* Ax = xb + (size_t)rowc * D;
            a[0] = *(const short8*)(Ax + (kh * 2 + 0) * 32 + kg * 8);
            a[1] = *(const short8*)(Ax + (kh * 2 + 1) * 32 + kg * 8);
        }
    };

    short8 aC[2], aN[2];
    stage(0, 0);
    loadA(0, aC);
    __syncthreads();  // drain stage 0

    for (int s = 0; s < 18; ++s) {
        int cur = s & 1;
        if (s < 17) { stage(s + 1, cur ^ 1); loadA(s + 1, aN); }
        const char* bb = Bc + cur * 32768;
#pragma unroll
        for (int kl = 0; kl < 2; ++kl) {
#pragma unroll
            for (int nt = 0; nt < 8; ++nt) {
                int col = nt * 16 + mrow;
                int rb = col * 128 + kl * 64 + kg * 16;
                int rs = rb ^ ((rb >> 4) & 0x70);
                short8 bh = *(const short8*)(bb + rs);
                short8 bl = *(const short8*)(bb + 16384 + rs);
                acc[nt] = __builtin_amdgcn_mfma_f32_16x16x32_bf16(aC[kl], bh, acc[nt], 0, 0, 0);
                acc[nt] = __builtin_amdgcn_mfma_f32_16x16x32_bf16(aC[kl], bl, acc[nt], 0, 0, 0);
            }
        }
        __syncthreads();  // drains stage s+1 loads; guards buffer reuse
        if (s < 17) { aC[0] = aN[0]; aC[1] = aN[1]; }
    }

    // epilogue: D layout col=lane&15, row=(lane>>4)*4+j (verified rounds 5-13)
#pragma unroll
    for (int nt = 0; nt < 8; ++nt) {
        int col = nt * 16 + mrow;
        float bb = bias[col];
#pragma unroll
        for (int j = 0; j < 4; ++j) {
            int nn = n0 + wave * 16 + kg * 4 + j;
            if (nn < N_NODES) {
                float v = acc[nt][j] + bb;
                out[(size_t)nn * D + col] = v > 0.f ? v : 0.f;
            }
        }
    }
}

// ---------------- FALLBACK path (small ws; never taken per R8-13 evidence) --
__global__ void __launch_bounds__(256)
count_fb_kernel(const int* __restrict__ ei, const int* __restrict__ et,
                int* __restrict__ cnt) {
    int e = blockIdx.x * 256 + threadIdx.x;
    if (e < E_EDGES) {
        int dst = ei[E_EDGES + e];
        int r = et[e];
        atomicAdd(&cnt[r * N_NODES + dst], 1);
    }
}

__global__ void __launch_bounds__(256)
scan1_kernel(int* __restrict__ off, int* __restrict__ part) {
    __shared__ int wsum[4];
    int tid = threadIdx.x, lane = tid & 63, wid = tid >> 6;
    int base = blockIdx.x * 1024 + tid * 4;
    int c0 = 0, c1 = 0, c2 = 0, c3 = 0;
    if (base + 0 < NR) c0 = off[base + 0];
    if (base + 1 < NR) c1 = off[base + 1];
    if (base + 2 < NR) c2 = off[base + 2];
    if (base + 3 < NR) c3 = off[base + 3];
    int ts = c0 + c1 + c2 + c3;
    int v = ts;
#pragma unroll
    for (int o = 1; o < 64; o <<= 1) {
        int u = __shfl_up(v, o, 64);
        if (lane >= o) v += u;
    }
    if (lane == 63) wsum[wid] = v;
    __syncthreads();
    int wbase = 0;
#pragma unroll
    for (int w = 0; w < 4; ++w)
        if (w < wid) wbase += wsum[w];
    int excl = wbase + v - ts;
    if (base + 0 < NR) off[base + 0] = excl;
    if (base + 1 < NR) off[base + 1] = excl + c0;
    if (base + 2 < NR) off[base + 2] = excl + c0 + c1;
    if (base + 3 < NR) off[base + 3] = excl + c0 + c1 + c2;
    if (tid == 0) part[blockIdx.x] = wsum[0] + wsum[1] + wsum[2] + wsum[3];
}

__global__ void __launch_bounds__(512)
scan2_kernel(int* __restrict__ part) {
    __shared__ int ws8[8];
    int t = threadIdx.x, lane = t & 63, w = t >> 6;
    int v = (t < SCAN_BLOCKS) ? part[t] : 0;
    int s = v;
#pragma unroll
    for (int o = 1; o < 64; o <<= 1) {
        int u = __shfl_up(s, o, 64);
        if (lane >= o) s += u;
    }
    if (lane == 63) ws8[w] = s;
    __syncthreads();
    int wb = 0;
#pragma unroll
    for (int i = 0; i < 8; ++i)
        if (i < w) wb += ws8[i];
    if (t < SCAN_BLOCKS) part[t] = wb + s - v;
}

__global__ void __launch_bounds__(256)
scan3_kernel(int* __restrict__ off, const int* __restrict__ part) {
    int p = part[blockIdx.x];
    int base = blockIdx.x * 1024 + threadIdx.x * 4;
#pragma unroll
    for (int i = 0; i < 4; ++i)
        if (base + i < NR) off[base + i] += p;
}

__global__ void __launch_bounds__(256)
bucket_atomic_kernel(const int* __restrict__ ei, const int* __restrict__ et,
                     int* __restrict__ off, uint_t* __restrict__ bucket) {
    int e = blockIdx.x * 256 + threadIdx.x;
    if (e < E_EDGES) {
        int src = ei[e];
        int dst = ei[E_EDGES + e];
        int r = et[e];
        int key = r * N_NODES + dst;
        int pos = atomicAdd(&off[key], 1);
        bucket[pos] = (uint_t)src | ((uint_t)(dst & 63) << 17) | ((uint_t)r << 23);
    }
}

__global__ void __launch_bounds__(256, 4)
fused_kernel(const float* __restrict__ x,
             const ushort_t* __restrict__ WtH, const ushort_t* __restrict__ WtL,
             const float* __restrict__ bias, const int* __restrict__ ends,
             const uint_t* __restrict__ bucket, float* __restrict__ out) {
    __shared__ float At[64][132];
    __shared__ float sinv[64];
    __shared__ int sEnd[64];
    __shared__ float bs[128];
    __shared__ int sBase;

    int tid = threadIdx.x;
    int lane = tid & 63;
    int wave = tid >> 6;
    int mrow = lane & 15;
    int kg = lane >> 4;
    int n0 = blockIdx.x * 64;
    if (tid < 128) bs[tid] = bias[tid];

    f32x4 acc[8];
#pragma unroll
    for (int t = 0; t < 8; ++t) acc[t] = (f32x4){0.f, 0.f, 0.f, 0.f};

    for (int r = 0; r < R; ++r) {
        __syncthreads();
#pragma unroll
        for (int u = 0; u < 33; ++u) ((float*)At)[tid + u * 256] = 0.f;
        if (tid < 64) {
            int n = n0 + tid;
            if (n > N_NODES - 1) n = N_NODES - 1;
            int key = r * N_NODES + n;
            int e1 = ends[key];
            int e0 = (key == 0) ? 0 : ends[key - 1];
            int c = e1 - e0;
            sinv[tid] = (c > 0) ? 1.0f / (float)c : 0.0f;
            sEnd[tid] = e1;
            if (tid == 0) sBase = e0;
        }
        __syncthreads();
        int base = sBase;
        int nItems = (sEnd[63] - base) << 5;

        for (int i = tid; i < nItems; i += 256) {
            uint_t v = bucket[base + (i >> 5)];
            int src = v & 0x1FFFF;
            int dl = (v >> 17) & 63;
            int ch = i & 31;
            float4 xv = *(const float4*)(x + (size_t)src * D + ch * 4);
            float* rp = &At[dl][ch * 4];
            atomicAdd(rp + 0, xv.x);
            atomicAdd(rp + 1, xv.y);
            atomicAdd(rp + 2, xv.z);
            atomicAdd(rp + 3, xv.w);
        }
        __syncthreads();

        const ushort_t* WH = WtH + ((size_t)r << 14);
        const ushort_t* WL = WtL + ((size_t)r << 14);
        int rw = wave * 16 + mrow;
        float iv = sinv[rw];
#pragma unroll
        for (int kstep = 0; kstep < 4; ++kstep) {
            int kofs = kstep * 32 + kg * 8;
            float4 f0 = *(const float4*)&At[rw][kofs];
            float4 f1 = *(const float4*)&At[rw][kofs + 4];
            float fv[8] = {f0.x, f0.y, f0.z, f0.w, f1.x, f1.y, f1.z, f1.w};
            short8 ah, al;
#pragma unroll
            for (int j = 0; j < 8; ++j) {
                float f = fv[j] * iv;
                ushort_t hb = f2bf(f);
                ah[j] = (short)hb;
                al[j] = (short)f2bf(f - bf2f(hb));
            }
#pragma unroll
            for (int nt = 0; nt < 8; ++nt) {
                int col = nt * 16 + mrow;
                short8 bh = *(const short8*)&WH[(size_t)col * D + kofs];
                short8 bl = *(const short8*)&WL[(size_t)col * D + kofs];
                acc[nt] = __builtin_amdgcn_mfma_f32_16x16x32_bf16(ah, bh, acc[nt], 0, 0, 0);
                acc[nt] = __builtin_amdgcn_mfma_f32_16x16x32_bf16(ah, bl, acc[nt], 0, 0, 0);
                acc[nt] = __builtin_amdgcn_mfma_f32_16x16x32_bf16(al, bh, acc[nt], 0, 0, 0);
            }
        }
    }

    {
        const ushort_t* WH = WtH + ((size_t)8 << 14);
        const ushort_t* WL = WtL + ((size_t)8 << 14);
        int n = n0 + wave * 16 + mrow;
#pragma unroll
        for (int kstep = 0; kstep < 4; ++kstep) {
            int kofs = kstep * 32 + kg * 8;
            float fv[8] = {0.f, 0.f, 0.f, 0.f, 0.f, 0.f, 0.f, 0.f};
            if (n < N_NODES) {
                const float4* xp = (const float4*)(x + (size_t)n * D + kofs);
                float4 f0 = xp[0], f1 = xp[1];
                fv[0] = f0.x; fv[1] = f0.y; fv[2] = f0.z; fv[3] = f0.w;
                fv[4] = f1.x; fv[5] = f1.y; fv[6] = f1.z; fv[7] = f1.w;
            }
            short8 ah, al;
#pragma unroll
            for (int j = 0; j < 8; ++j) {
                float f = fv[j];
                ushort_t hb = f2bf(f);
                ah[j] = (short)hb;
                al[j] = (short)f2bf(f - bf2f(hb));
            }
#pragma unroll
            for (int nt = 0; nt < 8; ++nt) {
                int col = nt * 16 + mrow;
                short8 bh = *(const short8*)&WH[(size_t)col * D + kofs];
                short8 bl = *(const short8*)&WL[(size_t)col * D + kofs];
                acc[nt] = __builtin_amdgcn_mfma_f32_16x16x32_bf16(ah, bh, acc[nt], 0, 0, 0);
                acc[nt] = __builtin_amdgcn_mfma_f32_16x16x32_bf16(ah, bl, acc[nt], 0, 0, 0);
                acc[nt] = __builtin_amdgcn_mfma_f32_16x16x32_bf16(al, bh, acc[nt], 0, 0, 0);
            }
        }
    }

#pragma unroll
    for (int nt = 0; nt < 8; ++nt) {
        int col = nt * 16 + mrow;
        float bb = bs[col];
#pragma unroll
        for (int j = 0; j < 4; ++j) {
            int nn = n0 + wave * 16 + kg * 4 + j;
            if (nn < N_NODES) {
                float v = acc[nt][j] + bb;
                out[(size_t)nn * D + col] = v > 0.f ? v : 0.f;
            }
        }
    }
}

extern "C" void kernel_launch(void* const* d_in, const int* in_sizes, int n_in,
                              void* d_out, int out_size, void* d_ws, size_t ws_size,
                              hipStream_t stream) {
    const float* x     = (const float*)d_in[0];
    const int*   ei    = (const int*)d_in[1];
    const int*   et    = (const int*)d_in[2];
    const float* W     = (const float*)d_in[3];
    const float* Wroot = (const float*)d_in[4];
    const float* b     = (const float*)d_in[5];
    float* out = (float*)d_out;
    int* ws = (int*)d_ws;

    if (ws_size >= BIG_WS_BYTES) {
        int* cnt = ws;                                        // NR ints
        int* slots = ws + NR;                                 // NR*16 ints
        ushort_t* WtH = (ushort_t*)(ws + NR + NR * SLOTS_K);  // 9*16384 ushorts
        ushort_t* WtL = WtH + 9 * 16384;
        ushort_t* Mh = WtL + 9 * 16384;                       // NR*D bf16-hi
        ushort_t* xb = Mh + (size_t)NR * D;                   // N*D bf16

        hipMemsetAsync(cnt, 0, (size_t)NR * sizeof(int), stream);
        xb_kernel<<<(N_NODES * D) / (256 * 8), 256, 0, stream>>>(x, xb);
        count_slots_kernel<<<(E_EDGES + 255) / 256, 256, 0, stream>>>(ei, et, cnt,
                                                                      slots);
        wt_kernel<<<36, 256, 0, stream>>>(W, Wroot, WtH, WtL);
        mean_kernel<<<NR / 16, 256, 0, stream>>>(xb, ei, et, cnt, slots, Mh);
        gemm_kernel<<<(N_NODES + 127) / 128, 512, 0, stream>>>(xb, Mh, WtH, WtL, cnt,
                                                               b, out);
    } else {
        int* off = ws;                                   // NR ints
        uint_t* bucket = (uint_t*)(ws + NR);             // E packed words
        ushort_t* WtH = (ushort_t*)(ws + NR + E_EDGES);  // 9*16384 ushorts
        ushort_t* WtL = WtH + 9 * 16384;

        hipMemsetAsync(off, 0, (size_t)NR * sizeof(int), stream);
        count_fb_kernel<<<(E_EDGES + 255) / 256, 256, 0, stream>>>(ei, et, off);
        wt_kernel<<<36, 256, 0, stream>>>(W, Wroot, WtH, WtL);
        scan1_kernel<<<SCAN_BLOCKS, 256, 0, stream>>>(off, (int*)bucket);
        scan2_kernel<<<1, 512, 0, stream>>>((int*)bucket);
        scan3_kernel<<<SCAN_BLOCKS, 256, 0, stream>>>(off, (int*)bucket);
        bucket_atomic_kernel<<<(E_EDGES + 255) / 256, 256, 0, stream>>>(ei, et, off,
                                                                        bucket);
        fused_kernel<<<(N_NODES + 63) / 64, 256, 0, stream>>>(x, WtH, WtL, b, off,
                                                              bucket, out);
    }
}